// Round 11
// baseline (463.692 us; speedup 1.0000x reference)
//
#include <hip/hip_runtime.h>
#include <hip/hip_bf16.h>

#define NH 8
#define BS_ 8
#define NQ_ 100
#define NK_ 17
#define LQ 1700            // NQ_*NK_
#define T_TOK 13600        // BS_*LQ
#define LEN_VV 34000

typedef __attribute__((ext_vector_type(8))) short short8v;
typedef __attribute__((ext_vector_type(8))) __bf16 bf16x8;
typedef __attribute__((ext_vector_type(4))) float f32x4;

__device__ __forceinline__ short f2bf(float f){
  __hip_bfloat16 h = __float2bfloat16(f);
  return *reinterpret_cast<short*>(&h);
}
__device__ __forceinline__ float bf2f(short s){
  return __uint_as_float(((uint)(unsigned short)s) << 16);
}

// ---------------- 128x128 MFMA GEMM (fp32 or bf16 A, bf16 out via LDS epilogue) -------
template<int EPI, int ADDA, int SWZ, int INB>
__global__ __launch_bounds__(256) void mgemm_k(const void* __restrict__ Av,
                                               const float* __restrict__ A2,
                                               const float* __restrict__ W,
                                               const float* __restrict__ bias,
                                               __hip_bfloat16* __restrict__ Cb,
                                               int M, int N, int K, int nbx){
  __shared__ short sh[128 * 136];
  short* As = sh;
  short* Ws = sh + 128 * 64;
  int j;
  if (SWZ){
    int total = gridDim.x;
    int q = total >> 3, r = total & 7;
    int x = blockIdx.x & 7, k = blockIdx.x >> 3;
    j = (x < r) ? x * (q + 1) + k : r * (q + 1) + (x - r) * q + k;
  } else {
    j = blockIdx.x;
  }
  const float* A = (const float*)Av;
  const short* Ab = (const short*)Av;
  const int tid = threadIdx.x;
  const int bm = (j / nbx) * 128, bn = (j % nbx) * 128;
  const int wave = tid >> 6, lane = tid & 63;
  const int wm = (wave >> 1) * 64, wn = (wave & 1) * 64;
  const int s = tid & 7;
  const int row0 = tid >> 3;
  f32x4 acc[4][4] = {};
  const int lrow = lane & 15, lk = lane >> 4;

  float4 ra[INB ? 1 : 8], rw[8];
  short8v rab[INB ? 4 : 1];
#pragma unroll
  for (int i = 0; i < 4; i++){
    int row = row0 + i * 32;
    int gr = bm + row;
    if (INB){
      short8v z = {};
      rab[INB ? i : 0] = (gr < M) ? *(const short8v*)(Ab + (size_t)gr * K + s * 8) : z;
    } else {
      float4 z = make_float4(0.f, 0.f, 0.f, 0.f);
      if (gr < M){
        const float* p = A + (size_t)gr * K + s * 8;
        float4 x0 = ((const float4*)p)[0], x1 = ((const float4*)p)[1];
        if (ADDA){
          const float* q2 = A2 + (size_t)gr * K + s * 8;
          float4 y0 = ((const float4*)q2)[0], y1 = ((const float4*)q2)[1];
          x0.x+=y0.x; x0.y+=y0.y; x0.z+=y0.z; x0.w+=y0.w;
          x1.x+=y1.x; x1.y+=y1.y; x1.z+=y1.z; x1.w+=y1.w;
        }
        ra[INB ? 0 : (2 * i)] = x0; ra[INB ? 0 : (2 * i + 1)] = x1;
      } else { ra[INB ? 0 : (2 * i)] = z; ra[INB ? 0 : (2 * i + 1)] = z; }
    }
    const float* q = W + (size_t)(bn + row) * K + s * 8;
    rw[2 * i] = ((const float4*)q)[0]; rw[2 * i + 1] = ((const float4*)q)[1];
  }

  for (int k0 = 0; k0 < K; k0 += 64){
#pragma unroll
    for (int i = 0; i < 4; i++){
      int row = row0 + i * 32;
      int sw = ((s ^ (row & 7)) << 3) + row * 64;
      if (INB){
        *(short8v*)&As[sw] = rab[INB ? i : 0];
      } else {
        float4 a0 = ra[INB ? 0 : (2 * i)], a1 = ra[INB ? 0 : (2 * i + 1)];
        short8v v;
        v[0]=f2bf(a0.x); v[1]=f2bf(a0.y); v[2]=f2bf(a0.z); v[3]=f2bf(a0.w);
        v[4]=f2bf(a1.x); v[5]=f2bf(a1.y); v[6]=f2bf(a1.z); v[7]=f2bf(a1.w);
        *(short8v*)&As[sw] = v;
      }
      float4 a0 = rw[2 * i], a1 = rw[2 * i + 1];
      short8v u;
      u[0]=f2bf(a0.x); u[1]=f2bf(a0.y); u[2]=f2bf(a0.z); u[3]=f2bf(a0.w);
      u[4]=f2bf(a1.x); u[5]=f2bf(a1.y); u[6]=f2bf(a1.z); u[7]=f2bf(a1.w);
      *(short8v*)&Ws[sw] = u;
    }
    __syncthreads();
    if (k0 + 64 < K){
#pragma unroll
      for (int i = 0; i < 4; i++){
        int row = row0 + i * 32;
        int gr = bm + row;
        if (INB){
          short8v z = {};
          rab[INB ? i : 0] = (gr < M) ? *(const short8v*)(Ab + (size_t)gr * K + k0 + 64 + s * 8) : z;
        } else {
          float4 z = make_float4(0.f, 0.f, 0.f, 0.f);
          if (gr < M){
            const float* p = A + (size_t)gr * K + k0 + 64 + s * 8;
            float4 x0 = ((const float4*)p)[0], x1 = ((const float4*)p)[1];
            if (ADDA){
              const float* q2 = A2 + (size_t)gr * K + k0 + 64 + s * 8;
              float4 y0 = ((const float4*)q2)[0], y1 = ((const float4*)q2)[1];
              x0.x+=y0.x; x0.y+=y0.y; x0.z+=y0.z; x0.w+=y0.w;
              x1.x+=y1.x; x1.y+=y1.y; x1.z+=y1.z; x1.w+=y1.w;
            }
            ra[INB ? 0 : (2 * i)] = x0; ra[INB ? 0 : (2 * i + 1)] = x1;
          } else { ra[INB ? 0 : (2 * i)] = z; ra[INB ? 0 : (2 * i + 1)] = z; }
        }
        const float* q = W + (size_t)(bn + row) * K + k0 + 64 + s * 8;
        rw[2 * i] = ((const float4*)q)[0]; rw[2 * i + 1] = ((const float4*)q)[1];
      }
    }
#pragma unroll
    for (int ks = 0; ks < 2; ks++){
      short8v af[4], bw[4];
      int slot = ks * 4 + lk;
#pragma unroll
      for (int m = 0; m < 4; m++){
        int r = wm + m * 16 + lrow;
        af[m] = *(const short8v*)&As[r * 64 + ((slot ^ (r & 7)) << 3)];
      }
#pragma unroll
      for (int n = 0; n < 4; n++){
        int r = wn + n * 16 + lrow;
        bw[n] = *(const short8v*)&Ws[r * 64 + ((slot ^ (r & 7)) << 3)];
      }
#pragma unroll
      for (int m = 0; m < 4; m++)
#pragma unroll
        for (int n = 0; n < 4; n++)
          acc[m][n] = __builtin_amdgcn_mfma_f32_16x16x32_bf16(
              __builtin_bit_cast(bf16x8, af[m]),
              __builtin_bit_cast(bf16x8, bw[n]), acc[m][n], 0, 0, 0);
    }
    __syncthreads();
  }
  const int STR = 136;
#pragma unroll
  for (int n = 0; n < 4; n++){
    int col = wn + n * 16 + lrow;
    float bsv = bias[bn + col];
#pragma unroll
    for (int m = 0; m < 4; m++){
#pragma unroll
      for (int i = 0; i < 4; i++){
        int row = wm + m * 16 + lk * 4 + i;
        float c = acc[m][n][i] + bsv;
        if (EPI == 1) c = fmaxf(c, 0.f);
        sh[row * STR + col] = f2bf(c);
      }
    }
  }
  __syncthreads();
#pragma unroll
  for (int it = 0; it < 8; it++){
    int r = it * 16 + (tid >> 4);
    int chunk = tid & 15;
    if (bm + r < M){
      uint4 v = *(const uint4*)((const char*)sh + r * 272 + chunk * 16);
      *(uint4*)((char*)Cb + ((size_t)(bm + r) * N + bn) * 2 + chunk * 16) = v;
    }
  }
}

// ---------------- 64x64 MFMA GEMM ----------------
template<int EPI, int OUTB, int INB, int DUALA>
__global__ __launch_bounds__(256) void g64_k(const void* __restrict__ Av,
                                             const void* __restrict__ A1v,
                                             const float* __restrict__ W0,
                                             const float* __restrict__ W1,
                                             int NSPLIT,
                                             const float* __restrict__ bias0,
                                             const float* __restrict__ bias1,
                                             const float* __restrict__ RES,
                                             float* __restrict__ Cf,
                                             __hip_bfloat16* __restrict__ Cb,
                                             int M, int N, int K, int sA){
  __shared__ short sh64[2 * 64 * 64];
  short* As = sh64;
  short* Ws = sh64 + 64 * 64;
  const int tid = threadIdx.x;
  const int bn = blockIdx.x * 64, bm = blockIdx.y * 64;
  const int wave = tid >> 6, lane = tid & 63;
  const int wm = (wave >> 1) * 32, wn = (wave & 1) * 32;
  const int s = tid & 7, row0 = tid >> 3;
  const int lrow = lane & 15, lk = lane >> 4;
  f32x4 acc[2][2] = {};

  for (int k0 = 0; k0 < K; k0 += 64){
#pragma unroll
    for (int i = 0; i < 2; i++){
      int row = row0 + i * 32;
      int sw = ((s ^ (row & 7)) << 3) + row * 64;
      short8v v = {};
      int gr = bm + row;
      if (gr < M){
        if (INB){
          v = *(const short8v*)((const short*)Av + (size_t)gr * sA + k0 + s * 8);
        } else {
          const float* Ap;
          if (DUALA) Ap = (k0 < 256) ? (const float*)Av + (size_t)gr * 256 + k0
                                     : (const float*)A1v + (size_t)gr * 256 + (k0 - 256);
          else Ap = (const float*)Av + (size_t)gr * sA + k0;
          float4 a0 = ((const float4*)(Ap + s * 8))[0];
          float4 a1 = ((const float4*)(Ap + s * 8))[1];
          v[0]=f2bf(a0.x); v[1]=f2bf(a0.y); v[2]=f2bf(a0.z); v[3]=f2bf(a0.w);
          v[4]=f2bf(a1.x); v[5]=f2bf(a1.y); v[6]=f2bf(a1.z); v[7]=f2bf(a1.w);
        }
      }
      *(short8v*)&As[sw] = v;
      int wr = bn + row;
      const float* Wp = (wr < NSPLIT) ? W0 + (size_t)wr * K + k0
                                      : W1 + (size_t)(wr - NSPLIT) * K + k0;
      float4 b0 = ((const float4*)(Wp + s * 8))[0];
      float4 b1 = ((const float4*)(Wp + s * 8))[1];
      short8v u;
      u[0]=f2bf(b0.x); u[1]=f2bf(b0.y); u[2]=f2bf(b0.z); u[3]=f2bf(b0.w);
      u[4]=f2bf(b1.x); u[5]=f2bf(b1.y); u[6]=f2bf(b1.z); u[7]=f2bf(b1.w);
      *(short8v*)&Ws[sw] = u;
    }
    __syncthreads();
#pragma unroll
    for (int ks = 0; ks < 2; ks++){
      int slot = ks * 4 + lk;
      short8v af[2], bw[2];
#pragma unroll
      for (int m = 0; m < 2; m++){
        int r = wm + m * 16 + lrow;
        af[m] = *(const short8v*)&As[r * 64 + ((slot ^ (r & 7)) << 3)];
      }
#pragma unroll
      for (int n = 0; n < 2; n++){
        int r = wn + n * 16 + lrow;
        bw[n] = *(const short8v*)&Ws[r * 64 + ((slot ^ (r & 7)) << 3)];
      }
#pragma unroll
      for (int m = 0; m < 2; m++)
#pragma unroll
        for (int n = 0; n < 2; n++)
          acc[m][n] = __builtin_amdgcn_mfma_f32_16x16x32_bf16(
              __builtin_bit_cast(bf16x8, af[m]),
              __builtin_bit_cast(bf16x8, bw[n]), acc[m][n], 0, 0, 0);
    }
    __syncthreads();
  }
  if (OUTB){
    const int STR = 72;
#pragma unroll
    for (int n = 0; n < 2; n++){
      int col = wn + n * 16 + lrow;
      int gc = bn + col;
      float bsv = (gc < NSPLIT) ? bias0[gc] : bias1[gc - NSPLIT];
#pragma unroll
      for (int m = 0; m < 2; m++){
#pragma unroll
        for (int i = 0; i < 4; i++){
          int row = wm + m * 16 + lk * 4 + i;
          float c = acc[m][n][i] + bsv;
          if (EPI == 1) c = fmaxf(c, 0.f);
          if (EPI == 2) c = 1.f / (1.f + expf(-c));
          sh64[row * STR + col] = f2bf(c);
        }
      }
    }
    __syncthreads();
#pragma unroll
    for (int it = 0; it < 2; it++){
      int r = it * 32 + (tid >> 3);
      int chunk = tid & 7;
      if (bm + r < M){
        uint4 v = *(const uint4*)((const char*)sh64 + r * 144 + chunk * 16);
        *(uint4*)((char*)Cb + ((size_t)(bm + r) * N + bn) * 2 + chunk * 16) = v;
      }
    }
  } else {
#pragma unroll
    for (int n = 0; n < 2; n++){
      int gc = bn + wn + n * 16 + lrow;
      float bsv = (gc < NSPLIT) ? bias0[gc] : bias1[gc - NSPLIT];
#pragma unroll
      for (int m = 0; m < 2; m++){
#pragma unroll
        for (int i = 0; i < 4; i++){
          int row = bm + wm + m * 16 + lk * 4 + i;
          if (row >= M) continue;
          float c = acc[m][n][i] + bsv;
          if (EPI == 1) c = fmaxf(c, 0.f);
          if (EPI == 2) c = 1.f / (1.f + expf(-c));
          if (EPI == 3) c += RES[(size_t)row * N + gc];
          Cf[(size_t)row * N + gc] = c;
        }
      }
    }
  }
}

// ---------------- fused GEMM (N=256) + residual + LayerNorm + permuted write ----------
// SITE 0: win — x = C + r0 + r1, LN, write transposed (b,q,k)->(b,k,q)
// SITE 2: ffn — x = C + r0, clip, LN, plain write
template<int SITE, int OUTB>
__global__ __launch_bounds__(512) void gln_k(const short* __restrict__ Abf,
                                             const float* __restrict__ W,
                                             const float* __restrict__ bias,
                                             const float* __restrict__ r0,
                                             const float* __restrict__ r1,
                                             const float* __restrict__ g,
                                             const float* __restrict__ be,
                                             void* __restrict__ outv,
                                             int M, int K){
  __shared__ short As[64 * 64];
  __shared__ short Ws[256 * 64];
  __shared__ float part[64][4][2];
  __shared__ float stats[64][2];
  const int tid = threadIdx.x;
  const int bm = blockIdx.x * 64;
  const int wave = tid >> 6, lane = tid & 63;
  const int wm = (wave >> 2) * 32, wn = (wave & 3) * 64;
  const int s = tid & 7, row0 = tid >> 3;
  const int lrow = lane & 15, lk = lane >> 4;
  f32x4 acc[2][4] = {};

  short8v pa = {};
  { int gr = bm + row0; if (gr < M) pa = *(const short8v*)(Abf + (size_t)gr * K + s * 8); }
  float4 pw[8];
#pragma unroll
  for (int i = 0; i < 4; i++){
    const float* wp = W + (size_t)(row0 + i * 64) * K + s * 8;
    pw[2 * i] = ((const float4*)wp)[0]; pw[2 * i + 1] = ((const float4*)wp)[1];
  }

  for (int k0 = 0; k0 < K; k0 += 64){
    *(short8v*)&As[row0 * 64 + ((s ^ (row0 & 7)) << 3)] = pa;
#pragma unroll
    for (int i = 0; i < 4; i++){
      int row = row0 + i * 64;
      float4 b0 = pw[2 * i], b1 = pw[2 * i + 1];
      short8v u;
      u[0]=f2bf(b0.x); u[1]=f2bf(b0.y); u[2]=f2bf(b0.z); u[3]=f2bf(b0.w);
      u[4]=f2bf(b1.x); u[5]=f2bf(b1.y); u[6]=f2bf(b1.z); u[7]=f2bf(b1.w);
      *(short8v*)&Ws[row * 64 + ((s ^ (row & 7)) << 3)] = u;
    }
    __syncthreads();
    if (k0 + 64 < K){
      int gr = bm + row0;
      pa = (short8v){};
      if (gr < M) pa = *(const short8v*)(Abf + (size_t)gr * K + k0 + 64 + s * 8);
#pragma unroll
      for (int i = 0; i < 4; i++){
        const float* wp = W + (size_t)(row0 + i * 64) * K + k0 + 64 + s * 8;
        pw[2 * i] = ((const float4*)wp)[0]; pw[2 * i + 1] = ((const float4*)wp)[1];
      }
    }
#pragma unroll
    for (int ks = 0; ks < 2; ks++){
      int slot = ks * 4 + lk;
      short8v af[2], bw[4];
#pragma unroll
      for (int m = 0; m < 2; m++){
        int r = wm + m * 16 + lrow;
        af[m] = *(const short8v*)&As[r * 64 + ((slot ^ (r & 7)) << 3)];
      }
#pragma unroll
      for (int n = 0; n < 4; n++){
        int r = wn + n * 16 + lrow;
        bw[n] = *(const short8v*)&Ws[r * 64 + ((slot ^ (r & 7)) << 3)];
      }
#pragma unroll
      for (int m = 0; m < 2; m++)
#pragma unroll
        for (int n = 0; n < 4; n++)
          acc[m][n] = __builtin_amdgcn_mfma_f32_16x16x32_bf16(
              __builtin_bit_cast(bf16x8, af[m]),
              __builtin_bit_cast(bf16x8, bw[n]), acc[m][n], 0, 0, 0);
    }
    __syncthreads();
  }

#pragma unroll
  for (int m = 0; m < 2; m++){
#pragma unroll
    for (int i = 0; i < 4; i++){
      int row = wm + m * 16 + lk * 4 + i;
      int grow = bm + row;
      float s1 = 0.f, s2 = 0.f;
      if (grow < M){
#pragma unroll
        for (int n = 0; n < 4; n++){
          int col = wn + n * 16 + lrow;
          float x = acc[m][n][i] + bias[col] + r0[(size_t)grow * 256 + col];
          if (SITE == 0) x += r1[(size_t)grow * 256 + col];
          if (SITE == 2) x = fminf(fmaxf(x, -65504.f), 65504.f);
          acc[m][n][i] = x;
          s1 += x; s2 += x * x;
        }
      }
#pragma unroll
      for (int msk = 1; msk <= 8; msk <<= 1){
        s1 += __shfl_xor(s1, msk, 64);
        s2 += __shfl_xor(s2, msk, 64);
      }
      if (lrow == 0){ part[row][wave & 3][0] = s1; part[row][wave & 3][1] = s2; }
    }
  }
  __syncthreads();
  if (tid < 64){
    float s1 = part[tid][0][0] + part[tid][1][0] + part[tid][2][0] + part[tid][3][0];
    float s2 = part[tid][0][1] + part[tid][1][1] + part[tid][2][1] + part[tid][3][1];
    float mean = s1 * (1.f / 256.f);
    float var = s2 * (1.f / 256.f) - mean * mean;
    stats[tid][0] = mean;
    stats[tid][1] = rsqrtf(fmaxf(var, 0.f) + 1e-5f);
  }
  __syncthreads();
#pragma unroll
  for (int m = 0; m < 2; m++){
#pragma unroll
    for (int i = 0; i < 4; i++){
      int row = wm + m * 16 + lk * 4 + i;
      int grow = bm + row;
      if (grow >= M) continue;
      float mean = stats[row][0], rstd = stats[row][1];
      size_t orow = grow;
      if (SITE == 0){
        int bi = grow / LQ; int rem = grow % LQ; int q = rem / NK_; int kk = rem % NK_;
        orow = (size_t)bi * LQ + kk * NQ_ + q;
      }
#pragma unroll
      for (int n = 0; n < 4; n++){
        int col = wn + n * 16 + lrow;
        float o = (acc[m][n][i] - mean) * rstd * g[col] + be[col];
        if (OUTB) ((short*)outv)[orow * 256 + col] = f2bf(o);
        else      ((float*)outv)[orow * 256 + col] = o;
      }
    }
  }
}

// ---------------- fused acr out-proj + LN + qpos add + OFFAW GEMM (N=384) ------------
// x = C + r0b(bf16), LN, orow = untranspose(grow), TQ = LN + qpos[orow];
// writes TQout bf16; then OFFAW[orow] = TQ @ [off_W|aw_W]^T + [off_b|aw_b]
__global__ __launch_bounds__(512) void glnoa_k(const short* __restrict__ Abf,
                                               const float* __restrict__ W,
                                               const float* __restrict__ bias,
                                               const short* __restrict__ r0b,
                                               const float* __restrict__ qpos,
                                               const float* __restrict__ g,
                                               const float* __restrict__ be,
                                               short* __restrict__ TQout,
                                               float* __restrict__ OFFAW,
                                               const float* __restrict__ off_W,
                                               const float* __restrict__ aw_W,
                                               const float* __restrict__ off_b,
                                               const float* __restrict__ aw_b,
                                               int M){
  __shared__ short smem[64 * 256 + 384 * 64];   // 80 KB union
  short* As1 = smem;                    // [64][64] per k-tile (phase 1)
  short* Ws1 = smem + 64 * 64;          // [256][64] per k-tile (phase 1)
  float* part = (float*)(smem + 64 * 64 + 256 * 64);   // [64][4][2]
  float* stats = part + 64 * 4 * 2;                    // [64][2]
  short* As2 = smem;                    // [64][256] (phase 2, full K)
  short* Ws2 = smem + 64 * 256;         // [384][64] per k-tile (phase 2)
  const int K = 256;
  const int tid = threadIdx.x;
  const int bm = blockIdx.x * 64;
  const int wave = tid >> 6, lane = tid & 63;
  const int wm = (wave >> 2) * 32, wn = (wave & 3) * 64;
  const int s = tid & 7, row0 = tid >> 3;
  const int lrow = lane & 15, lk = lane >> 4;
  f32x4 acc[2][4] = {};

  short8v pa = {};
  { int gr = bm + row0; if (gr < M) pa = *(const short8v*)(Abf + (size_t)gr * K + s * 8); }
  float4 pw[8];
#pragma unroll
  for (int i = 0; i < 4; i++){
    const float* wp = W + (size_t)(row0 + i * 64) * K + s * 8;
    pw[2 * i] = ((const float4*)wp)[0]; pw[2 * i + 1] = ((const float4*)wp)[1];
  }
  for (int k0 = 0; k0 < K; k0 += 64){
    *(short8v*)&As1[row0 * 64 + ((s ^ (row0 & 7)) << 3)] = pa;
#pragma unroll
    for (int i = 0; i < 4; i++){
      int row = row0 + i * 64;
      float4 b0 = pw[2 * i], b1 = pw[2 * i + 1];
      short8v u;
      u[0]=f2bf(b0.x); u[1]=f2bf(b0.y); u[2]=f2bf(b0.z); u[3]=f2bf(b0.w);
      u[4]=f2bf(b1.x); u[5]=f2bf(b1.y); u[6]=f2bf(b1.z); u[7]=f2bf(b1.w);
      *(short8v*)&Ws1[row * 64 + ((s ^ (row & 7)) << 3)] = u;
    }
    __syncthreads();
    if (k0 + 64 < K){
      int gr = bm + row0;
      pa = (short8v){};
      if (gr < M) pa = *(const short8v*)(Abf + (size_t)gr * K + k0 + 64 + s * 8);
#pragma unroll
      for (int i = 0; i < 4; i++){
        const float* wp = W + (size_t)(row0 + i * 64) * K + k0 + 64 + s * 8;
        pw[2 * i] = ((const float4*)wp)[0]; pw[2 * i + 1] = ((const float4*)wp)[1];
      }
    }
#pragma unroll
    for (int ks = 0; ks < 2; ks++){
      int slot = ks * 4 + lk;
      short8v af[2], bw[4];
#pragma unroll
      for (int m = 0; m < 2; m++){
        int r = wm + m * 16 + lrow;
        af[m] = *(const short8v*)&As1[r * 64 + ((slot ^ (r & 7)) << 3)];
      }
#pragma unroll
      for (int n = 0; n < 4; n++){
        int r = wn + n * 16 + lrow;
        bw[n] = *(const short8v*)&Ws1[r * 64 + ((slot ^ (r & 7)) << 3)];
      }
#pragma unroll
      for (int m = 0; m < 2; m++)
#pragma unroll
        for (int n = 0; n < 4; n++)
          acc[m][n] = __builtin_amdgcn_mfma_f32_16x16x32_bf16(
              __builtin_bit_cast(bf16x8, af[m]),
              __builtin_bit_cast(bf16x8, bw[n]), acc[m][n], 0, 0, 0);
    }
    __syncthreads();
  }
  // residual (bf16) + partial sums
#pragma unroll
  for (int m = 0; m < 2; m++){
#pragma unroll
    for (int i = 0; i < 4; i++){
      int row = wm + m * 16 + lk * 4 + i;
      int grow = bm + row;
      float s1 = 0.f, s2 = 0.f;
      if (grow < M){
#pragma unroll
        for (int n = 0; n < 4; n++){
          int col = wn + n * 16 + lrow;
          float x = acc[m][n][i] + bias[col] + bf2f(r0b[(size_t)grow * 256 + col]);
          acc[m][n][i] = x;
          s1 += x; s2 += x * x;
        }
      }
#pragma unroll
      for (int msk = 1; msk <= 8; msk <<= 1){
        s1 += __shfl_xor(s1, msk, 64);
        s2 += __shfl_xor(s2, msk, 64);
      }
      if (lrow == 0){ part[(row * 4 + (wave & 3)) * 2] = s1; part[(row * 4 + (wave & 3)) * 2 + 1] = s2; }
    }
  }
  __syncthreads();
  if (tid < 64){
    float s1 = part[(tid * 4 + 0) * 2] + part[(tid * 4 + 1) * 2] + part[(tid * 4 + 2) * 2] + part[(tid * 4 + 3) * 2];
    float s2 = part[(tid * 4 + 0) * 2 + 1] + part[(tid * 4 + 1) * 2 + 1] + part[(tid * 4 + 2) * 2 + 1] + part[(tid * 4 + 3) * 2 + 1];
    float mean = s1 * (1.f / 256.f);
    float var = s2 * (1.f / 256.f) - mean * mean;
    stats[tid * 2] = mean;
    stats[tid * 2 + 1] = rsqrtf(fmaxf(var, 0.f) + 1e-5f);
  }
  __syncthreads();
  // normalize, add qpos, write TQout + stage TQ into As2 (bf16, swizzled)
#pragma unroll
  for (int m = 0; m < 2; m++){
#pragma unroll
    for (int i = 0; i < 4; i++){
      int row = wm + m * 16 + lk * 4 + i;
      int grow = bm + row;
      float mean = stats[row * 2], rstd = stats[row * 2 + 1];
      size_t orow = 0;
      if (grow < M){
        int bi = grow / LQ; int rem = grow % LQ; int kk = rem / NQ_; int q = rem % NQ_;
        orow = (size_t)bi * LQ + q * NK_ + kk;
      }
#pragma unroll
      for (int n = 0; n < 4; n++){
        int col = wn + n * 16 + lrow;
        float tq = 0.f;
        if (grow < M){
          float o = (acc[m][n][i] - mean) * rstd * g[col] + be[col];
          tq = o + qpos[orow * 256 + col];
          TQout[orow * 256 + col] = f2bf(tq);
        }
        As2[row * 256 + ((((col >> 3) ^ (row & 7)) << 3) + (col & 7))] = f2bf(tq);
      }
    }
  }
  __syncthreads();
  // phase 2: OFFAW = TQ @ [off_W|aw_W]^T  (N=384, K=256)
  const int wm2 = (wave >> 2) * 32, wn2 = (wave & 3) * 96;
  f32x4 acc2[2][6] = {};
  for (int k0 = 0; k0 < 256; k0 += 64){
#pragma unroll
    for (int it = 0; it < 6; it++){
      int wr = row0 + it * 64;   // 0..383
      const float* Wp = (wr < 256) ? off_W + (size_t)wr * 256 + k0
                                   : aw_W + (size_t)(wr - 256) * 256 + k0;
      float4 b0 = ((const float4*)(Wp + s * 8))[0];
      float4 b1 = ((const float4*)(Wp + s * 8))[1];
      short8v u;
      u[0]=f2bf(b0.x); u[1]=f2bf(b0.y); u[2]=f2bf(b0.z); u[3]=f2bf(b0.w);
      u[4]=f2bf(b1.x); u[5]=f2bf(b1.y); u[6]=f2bf(b1.z); u[7]=f2bf(b1.w);
      *(short8v*)&Ws2[wr * 64 + ((s ^ (wr & 7)) << 3)] = u;
    }
    __syncthreads();
#pragma unroll
    for (int ks = 0; ks < 2; ks++){
      int slotl = ks * 4 + lk;
      int slotg = (k0 >> 3) + slotl;
      short8v af[2], bw[6];
#pragma unroll
      for (int m = 0; m < 2; m++){
        int r = wm2 + m * 16 + lrow;
        af[m] = *(const short8v*)&As2[r * 256 + ((slotg ^ (r & 7)) << 3)];
      }
#pragma unroll
      for (int n = 0; n < 6; n++){
        int r = wn2 + n * 16 + lrow;
        bw[n] = *(const short8v*)&Ws2[r * 64 + ((slotl ^ (r & 7)) << 3)];
      }
#pragma unroll
      for (int m = 0; m < 2; m++)
#pragma unroll
        for (int n = 0; n < 6; n++)
          acc2[m][n] = __builtin_amdgcn_mfma_f32_16x16x32_bf16(
              __builtin_bit_cast(bf16x8, af[m]),
              __builtin_bit_cast(bf16x8, bw[n]), acc2[m][n], 0, 0, 0);
    }
    __syncthreads();
  }
#pragma unroll
  for (int m = 0; m < 2; m++){
#pragma unroll
    for (int i = 0; i < 4; i++){
      int row = wm2 + m * 16 + lk * 4 + i;
      int grow = bm + row;
      if (grow >= M) continue;
      int bi = grow / LQ; int rem = grow % LQ; int kk = rem / NQ_; int q = rem % NQ_;
      size_t orow = (size_t)bi * LQ + q * NK_ + kk;
#pragma unroll
      for (int n = 0; n < 6; n++){
        int col = wn2 + n * 16 + lrow;
        float c = acc2[m][n][i] + ((col < 256) ? off_b[col] : aw_b[col - 256]);
        OFFAW[orow * 384 + col] = c;
      }
    }
  }
}

// ---------------- fused gate GEMM (K=512) + sigmoid + combine + LN ----------------
__global__ __launch_bounds__(512) void gateln_k(const short* __restrict__ TQ,
                                                const short* __restrict__ T2,
                                                const float* __restrict__ W,
                                                const float* __restrict__ bias,
                                                const float* __restrict__ g,
                                                const float* __restrict__ be,
                                                float* __restrict__ out, int M){
  __shared__ short sh[64 * 64 + 512 * 64];   // As | Ws ; reused as gbuf[64][520]
  short* As = sh;
  short* Ws = sh + 64 * 64;
  const int tid = threadIdx.x;
  const int bm = blockIdx.x * 64;
  const int wave = tid >> 6, lane = tid & 63;
  const int wm = (wave >> 2) * 32, wn = (wave & 3) * 128;
  const int s = tid & 7, row0 = tid >> 3;
  const int lrow = lane & 15, lk = lane >> 4;
  f32x4 acc[2][8] = {};

  for (int k0 = 0; k0 < 512; k0 += 64){
    {
      short8v v = {};
      int gr = bm + row0;
      if (gr < M){
        v = (k0 < 256) ? *(const short8v*)(TQ + (size_t)gr * 256 + k0 + s * 8)
                       : *(const short8v*)(T2 + (size_t)gr * 256 + (k0 - 256) + s * 8);
      }
      *(short8v*)&As[row0 * 64 + ((s ^ (row0 & 7)) << 3)] = v;
    }
#pragma unroll
    for (int i = 0; i < 8; i++){
      int row = row0 + i * 64;
      const float* wp = W + (size_t)row * 512 + k0 + s * 8;
      float4 b0 = ((const float4*)wp)[0], b1 = ((const float4*)wp)[1];
      short8v u;
      u[0]=f2bf(b0.x); u[1]=f2bf(b0.y); u[2]=f2bf(b0.z); u[3]=f2bf(b0.w);
      u[4]=f2bf(b1.x); u[5]=f2bf(b1.y); u[6]=f2bf(b1.z); u[7]=f2bf(b1.w);
      *(short8v*)&Ws[row * 64 + ((s ^ (row & 7)) << 3)] = u;
    }
    __syncthreads();
#pragma unroll
    for (int ks = 0; ks < 2; ks++){
      int slot = ks * 4 + lk;
      short8v af[2], bw[8];
#pragma unroll
      for (int m = 0; m < 2; m++){
        int r = wm + m * 16 + lrow;
        af[m] = *(const short8v*)&As[r * 64 + ((slot ^ (r & 7)) << 3)];
      }
#pragma unroll
      for (int n = 0; n < 8; n++){
        int r = wn + n * 16 + lrow;
        bw[n] = *(const short8v*)&Ws[r * 64 + ((slot ^ (r & 7)) << 3)];
      }
#pragma unroll
      for (int m = 0; m < 2; m++)
#pragma unroll
        for (int n = 0; n < 8; n++)
          acc[m][n] = __builtin_amdgcn_mfma_f32_16x16x32_bf16(
              __builtin_bit_cast(bf16x8, af[m]),
              __builtin_bit_cast(bf16x8, bw[n]), acc[m][n], 0, 0, 0);
    }
    __syncthreads();
  }
  short* gb = sh;
  const int GSTR = 520;
#pragma unroll
  for (int n = 0; n < 8; n++){
    int col = wn + n * 16 + lrow;
    float bsv = bias[col];
#pragma unroll
    for (int m = 0; m < 2; m++){
#pragma unroll
      for (int i = 0; i < 4; i++){
        int row = wm + m * 16 + lk * 4 + i;
        float c = acc[m][n][i] + bsv;
        gb[row * GSTR + col] = f2bf(1.f / (1.f + __expf(-c)));
      }
    }
  }
  __syncthreads();
  {
    int row = tid >> 3, cg = tid & 7;
    int grow = bm + row;
    float x[32];
    float s1 = 0.f, s2 = 0.f;
    if (grow < M){
#pragma unroll
      for (int jv = 0; jv < 4; jv++){
        int c0 = cg * 32 + jv * 8;
        short8v aqv = *(const short8v*)(TQ + (size_t)grow * 256 + c0);
        short8v t2v = *(const short8v*)(T2 + (size_t)grow * 256 + c0);
#pragma unroll
        for (int jj = 0; jj < 8; jj++){
          float g1 = bf2f(gb[row * GSTR + c0 + jj]);
          float g2 = bf2f(gb[row * GSTR + 256 + c0 + jj]);
          float xv = g1 * bf2f(aqv[jj]) + g2 * bf2f(t2v[jj]);
          x[jv * 8 + jj] = xv; s1 += xv; s2 += xv * xv;
        }
      }
    }
    s1 += __shfl_xor(s1, 1, 64); s2 += __shfl_xor(s2, 1, 64);
    s1 += __shfl_xor(s1, 2, 64); s2 += __shfl_xor(s2, 2, 64);
    s1 += __shfl_xor(s1, 4, 64); s2 += __shfl_xor(s2, 4, 64);
    float mean = s1 * (1.f / 256.f);
    float var = s2 * (1.f / 256.f) - mean * mean;
    float rstd = rsqrtf(fmaxf(var, 0.f) + 1e-5f);
    if (grow < M){
#pragma unroll
      for (int jv = 0; jv < 4; jv++){
        int c0 = cg * 32 + jv * 8;
        float4 o0, o1;
#pragma unroll
        for (int jj = 0; jj < 8; jj++){
          int c = c0 + jj;
          float o = (x[jv * 8 + jj] - mean) * rstd * g[c] + be[c];
          if (jj < 4) ((float*)&o0)[jj] = o; else ((float*)&o1)[jj - 4] = o;
        }
        *(float4*)(out + (size_t)grow * 256 + c0) = o0;
        *(float4*)(out + (size_t)grow * 256 + c0 + 4) = o1;
      }
    }
  }
}

// ---------------- MFMA MHA ----------------
template<int TP, int NSPL>
__global__ __launch_bounds__(256) void mha_mfma_k(const short* __restrict__ qkv,
                                                  __hip_bfloat16* __restrict__ out, int S){
  constexpr int MT = TP / 16;
  constexpr int KSTEPS = (TP + 31) / 32;
  constexpr int KS32 = KSTEPS * 32;
  constexpr int VSTRB = (KS32 == 128) ? 256 : 128;
  constexpr int CH = (MT + NSPL - 1) / NSPL;
  __shared__ short QK[2][TP][64];
  __shared__ short Vt[2][32][VSTRB / 2];
  __shared__ float Sc[2][16][128];
  __shared__ float rinv[2][16];

  const int tid = threadIdx.x;
  const int bid = blockIdx.x;
  const int batch = bid / (4 * NSPL);
  const int rem = bid % (4 * NSPL);
  const int hp = rem / NSPL;
  const int half = rem % NSPL;
  const int mtlo = half * CH;
  const int mthi = (mtlo + CH < MT) ? (mtlo + CH) : MT;
  const int wave = tid >> 6, lane = tid & 63;
  const int hh = wave >> 1, wsub = wave & 1;
  const int lrow = lane & 15, lk = lane >> 4;
  const float scale = 0.17677669529663687f;
  const size_t qbase = (size_t)batch * S * 768;

  for (int idx = tid; idx < 2 * TP * 4; idx += 256){
    int h2 = idx >= TP * 4;
    int rm = idx - h2 * TP * 4;
    int j = rm >> 2, s = rm & 3;
    int h = hp * 2 + h2;
    short8v qv = {}, kv = {};
    if (j < S){
      const short* p = qkv + qbase + (size_t)j * 768 + h * 32 + s * 8;
      qv = *(const short8v*)p;
      kv = *(const short8v*)(p + 256);
    }
    *(short8v*)&QK[h2][j][(s ^ (j & 7)) << 3] = qv;
    *(short8v*)&QK[h2][j][((s + 4) ^ (j & 7)) << 3] = kv;
  }
  for (int idx = tid; idx < 2 * KS32 * 4; idx += 256){
    int h2 = idx >= KS32 * 4;
    int rm = idx - h2 * KS32 * 4;
    int j = rm >> 2, e8 = rm & 3;
    int h = hp * 2 + h2;
    short8v v = {};
    if (j < S) v = *(const short8v*)(qkv + qbase + (size_t)j * 768 + h * 32 + 512 + e8 * 8);
#pragma unroll
    for (int c = 0; c < 8; c++){
      int e = e8 * 8 + c;
      char* pb = (char*)&Vt[h2][0][0] + e * VSTRB + (((j >> 3) ^ (e & 7)) << 4) + ((j & 7) << 1);
      *(short*)pb = v[c];
    }
  }
  __syncthreads();

  for (int mt = mtlo; mt < mthi; mt++){
    for (int nt = wsub; nt < MT; nt += 2){
      int ar = mt * 16 + lrow;
      short8v aq = *(const short8v*)&QK[hh][ar][(lk ^ (ar & 7)) << 3];
      int br = nt * 16 + lrow;
      short8v bk = *(const short8v*)&QK[hh][br][((lk + 4) ^ (br & 7)) << 3];
      f32x4 z = {};
      f32x4 d = __builtin_amdgcn_mfma_f32_16x16x32_bf16(
          __builtin_bit_cast(bf16x8, aq), __builtin_bit_cast(bf16x8, bk), z, 0, 0, 0);
#pragma unroll
      for (int i = 0; i < 4; i++){
        int rr = lk * 4 + i;
        int c = nt * 16 + lrow;
        Sc[hh][rr][(((c >> 2) ^ (rr & 7)) << 2) + (c & 3)] = d[i] * scale;
      }
    }
    __syncthreads();
    if (wsub == 0){
      int rr = lane >> 2, p = lane & 3;
      int grow = mt * 16 + rr;
      int Seff = (grow < S) ? S : 0;
      float mx = -1e30f;
#pragma unroll
      for (int m = 0; m < KSTEPS; m++){
        int j = p + 4 * m;
#pragma unroll
        for (int hf = 0; hf < 2; hf++){
          int ls = 2 * j + hf;
          float4 v = *(const float4*)&Sc[hh][rr][(ls ^ (rr & 7)) << 2];
          int c0 = ls * 4;
          mx = fmaxf(mx, (c0 + 0 < Seff) ? v.x : -1e30f);
          mx = fmaxf(mx, (c0 + 1 < Seff) ? v.y : -1e30f);
          mx = fmaxf(mx, (c0 + 2 < Seff) ? v.z : -1e30f);
          mx = fmaxf(mx, (c0 + 3 < Seff) ? v.w : -1e30f);
        }
      }
      mx = fmaxf(mx, __shfl_xor(mx, 1, 64));
      mx = fmaxf(mx, __shfl_xor(mx, 2, 64));
      float sum = 0.f;
#pragma unroll
      for (int m = 0; m < KSTEPS; m++){
        int j = p + 4 * m;
        float ev[8];
#pragma unroll
        for (int hf = 0; hf < 2; hf++){
          int ls = 2 * j + hf;
          float4 v = *(const float4*)&Sc[hh][rr][(ls ^ (rr & 7)) << 2];
          int c0 = ls * 4;
          ev[hf * 4 + 0] = (c0 + 0 < Seff) ? __expf(v.x - mx) : 0.f;
          ev[hf * 4 + 1] = (c0 + 1 < Seff) ? __expf(v.y - mx) : 0.f;
          ev[hf * 4 + 2] = (c0 + 2 < Seff) ? __expf(v.z - mx) : 0.f;
          ev[hf * 4 + 3] = (c0 + 3 < Seff) ? __expf(v.w - mx) : 0.f;
        }
        short8v pb;
#pragma unroll
        for (int q2 = 0; q2 < 8; q2++){ pb[q2] = f2bf(ev[q2]); sum += ev[q2]; }
        *(short8v*)((char*)&Sc[hh][rr][0] + ((j ^ (rr & 7)) << 4)) = pb;
      }
      sum += __shfl_xor(sum, 1, 64);
      sum += __shfl_xor(sum, 2, 64);
      if (p == 0) rinv[hh][rr] = (sum > 0.f) ? 1.f / sum : 0.f;
    }
    __syncthreads();
    {
      int nt2 = wsub;
      f32x4 acc = {};
#pragma unroll
      for (int ks = 0; ks < KSTEPS; ks++){
        int slot = ks * 4 + lk;
        short8v ap = *(const short8v*)((const char*)&Sc[hh][lrow][0] + ((slot ^ (lrow & 7)) << 4));
        int e = nt2 * 16 + lrow;
        short8v bv = *(const short8v*)((const char*)&Vt[hh][0][0] + e * VSTRB + ((slot ^ (e & 7)) << 4));
        acc = __builtin_amdgcn_mfma_f32_16x16x32_bf16(
            __builtin_bit_cast(bf16x8, ap), __builtin_bit_cast(bf16x8, bv), acc, 0, 0, 0);
      }
      int h = hp * 2 + hh;
#pragma unroll
      for (int i = 0; i < 4; i++){
        int row = mt * 16 + lk * 4 + i;
        if (row < S){
          float rv = rinv[hh][lk * 4 + i];
          out[((size_t)batch * S + row) * 256 + h * 32 + nt2 * 16 + lrow] =
              __float2bfloat16(acc[i] * rv);
        }
      }
    }
    __syncthreads();
  }
}

// ---------------- deformable sampling, two-phase; bf16 out ----------------
__global__ __launch_bounds__(256) void deform_k(const __hip_bfloat16* __restrict__ val,
                                                const float* __restrict__ offaw,
                                                const float* __restrict__ ref,
                                                unsigned int* __restrict__ outb){
  __shared__ uint2 meta[32][16][4];
  const int tid = threadIdx.x;
  const int t0 = blockIdx.x * 4;
  {
    int g = tid >> 3;
    int pair = tid & 7;
    int lt = g >> 3, h = g & 7;
    int t = t0 + lt;
    int b = t / LQ;
    int p0 = pair * 2;
    int l = p0 >> 2;
    const int starts[4] = {0, 25600, 32000, 33600};
    const int HS[4] = {160, 80, 40, 20};
    int w = HS[l];
    const float* ap = offaw + (size_t)t * 384 + 256 + h * 16;
    float a0 = ap[p0];
    float a1 = ap[p0 + 1];
    float mx = fmaxf(a0, a1);
#pragma unroll
    for (int m = 1; m <= 4; m <<= 1) mx = fmaxf(mx, __shfl_xor(mx, m, 64));
    float e0 = expf(a0 - mx), e1 = expf(a1 - mx);
    float s = e0 + e1;
#pragma unroll
    for (int m = 1; m <= 4; m <<= 1) s += __shfl_xor(s, m, 64);
    float inv = 1.f / s;
    float rx = ref[((size_t)t * 4 + l) * 2 + 0];
    float ry = ref[((size_t)t * 4 + l) * 2 + 1];
    float4 ov = *(const float4*)(offaw + (size_t)t * 384 + h * 32 + l * 8 + p0 * 2);
    int vbase = (b * LEN_VV + starts[l]) * 128 + h * 16;
#pragma unroll
    for (int pp = 0; pp < 2; pp++){
      float wgt = (pp ? e1 : e0) * inv;
      float px = rx * w + (pp ? ov.z : ov.x) - 0.5f;
      float py = ry * w + (pp ? ov.w : ov.y) - 0.5f;
      float x0f = floorf(px), y0f = floorf(py);
      float lx = px - x0f, ly = py - y0f;
      int x0 = (int)x0f, y0 = (int)y0f;
#pragma unroll
      for (int c = 0; c < 4; c++){
        int dx = c & 1, dy = c >> 1;
        int xi = x0 + dx, yi = y0 + dy;
        bool ok = (xi >= 0) & (xi < w) & (yi >= 0) & (yi < w);
        float cw = ok ? wgt * (dx ? lx : 1.f - lx) * (dy ? ly : 1.f - ly) : 0.f;
        uint idx = ok ? (uint)(vbase + (yi * w + xi) * 128) : 0u;
        uint2 m2; m2.x = idx; m2.y = __float_as_uint(cw);
        meta[g][p0 + pp][c] = m2;
      }
    }
  }
  __syncthreads();
  const uint2* V2 = (const uint2*)val;
  int sg = tid >> 3, lane8 = tid & 7;
  int lt = sg >> 3, h = sg & 7;
  int t = t0 + lt;
  float a0 = 0.f, a1 = 0.f, a2 = 0.f, a3 = 0.f;
#pragma unroll 4
  for (int c = 0; c < 64; c++){
    uint2 mw = meta[sg][c >> 2][c & 3];
    float wv = __uint_as_float(mw.y);
    uint2 v = V2[(size_t)(mw.x >> 1) + lane8];
    a0 += wv * __uint_as_float(v.x << 16);
    a1 += wv * __uint_as_float(v.x & 0xffff0000u);
    a2 += wv * __uint_as_float(v.y << 16);
    a3 += wv * __uint_as_float(v.y & 0xffff0000u);
  }
  uint2 u;
  u.x = ((uint)(unsigned short)f2bf(a1) << 16) | (uint)(unsigned short)f2bf(a0);
  u.y = ((uint)(unsigned short)f2bf(a3) << 16) | (uint)(unsigned short)f2bf(a2);
  ((uint2*)outb)[((size_t)t * 256 + h * 32) / 4 + lane8] = u;
}

extern "C" void kernel_launch(void* const* d_in, const int* in_sizes, int n_in,
                              void* d_out, int out_size, void* d_ws, size_t ws_size,
                              hipStream_t stream){
  const float* tgt_pose = (const float*)d_in[0];
  const float* qpos     = (const float*)d_in[1];
  const float* refp     = (const float*)d_in[2];
  const float* memory   = (const float*)d_in[3];
  const float* win_Wqkv = (const float*)d_in[4];
  const float* win_bqkv = (const float*)d_in[5];
  const float* win_Wo   = (const float*)d_in[6];
  const float* win_bo   = (const float*)d_in[7];
  const float* win_ng   = (const float*)d_in[8];
  const float* win_nb   = (const float*)d_in[9];
  const float* acr_Wqkv = (const float*)d_in[10];
  const float* acr_bqkv = (const float*)d_in[11];
  const float* acr_Wo   = (const float*)d_in[12];
  const float* acr_bo   = (const float*)d_in[13];
  const float* acr_ng   = (const float*)d_in[14];
  const float* acr_nb   = (const float*)d_in[15];
  const float* off_W    = (const float*)d_in[16];
  const float* off_b    = (const float*)d_in[17];
  const float* aw_W     = (const float*)d_in[18];
  const float* aw_b     = (const float*)d_in[19];
  const float* val_W    = (const float*)d_in[20];
  const float* val_b    = (const float*)d_in[21];
  const float* outp_W   = (const float*)d_in[22];
  const float* outp_b   = (const float*)d_in[23];
  const float* gate_W   = (const float*)d_in[24];
  const float* gate_b   = (const float*)d_in[25];
  const float* gate_ng  = (const float*)d_in[26];
  const float* gate_nb  = (const float*)d_in[27];
  const float* ffn_W1   = (const float*)d_in[28];
  const float* ffn_b1   = (const float*)d_in[29];
  const float* ffn_W2   = (const float*)d_in[30];
  const float* ffn_b2   = (const float*)d_in[31];
  const float* n2_g     = (const float*)d_in[32];
  const float* n2_b     = (const float*)d_in[33];

  float* out = (float*)d_out;
  char* ws = (char*)d_ws;
  const size_t TB = (size_t)T_TOK * 256 * 4;
  float* B2 = (float*)(ws);                                 // fp32 tgt3
  char* p = ws + TB;
  short* B1b = (short*)p;  p += (size_t)T_TOK * 256 * 2;    // bf16 tgt1 (b,k,q)
  short* Qb  = (short*)p;  p += (size_t)T_TOK * 768 * 2;    // bf16 qkv
  short* ABF = (short*)p;  p += (size_t)T_TOK * 256 * 2;    // bf16 attn/deform out
  short* TQb = (short*)p;  p += (size_t)T_TOK * 256 * 2;    // bf16 tgt_q
  short* T2b = (short*)p;  p += (size_t)T_TOK * 256 * 2;    // bf16 t2
  float* OFFAW = (float*)p; p += (size_t)T_TOK * 384 * 4;   // off|aw logits
  char* Vregion = p;
  __hip_bfloat16* V = (__hip_bfloat16*)Vregion;             // 139 MB
  short* FF = (short*)Vregion;                              // overlay (V dead after deform)

  const int GM128 = (T_TOK + 127) / 128;   // 107
  const int GM64  = (T_TOK + 63) / 64;     // 213
  const int BIG = 1 << 30;

  // 1. value proj (XCD-swizzled) -> V bf16
  mgemm_k<0,0,1,0><<<2 * 2125, 256, 0, stream>>>(memory, nullptr, val_W, val_b, V, BS_ * LEN_VV, 256, 256, 2);
  // 2. within qkv (A = tgt_pose + qpos fused) -> Qb
  mgemm_k<0,1,0,0><<<6 * GM128, 256, 0, stream>>>(tgt_pose, qpos, win_Wqkv, win_bqkv, (__hip_bfloat16*)Qb, T_TOK, 768, 256, 6);
  // 3. within attention (S=17)
  mha_mfma_k<32,1><<<800 * 4, 256, 0, stream>>>(Qb, (__hip_bfloat16*)ABF, 17);
  // 4. out proj + LN(tgt_pose+qpos+C) + transpose write -> B1b bf16 (b,k,q)
  gln_k<0,1><<<GM64, 512, 0, stream>>>(ABF, win_Wo, win_bo, tgt_pose, qpos, win_ng, win_nb, B1b, T_TOK, 256);
  // 5. across qkv (A = B1b bf16) -> Qb
  mgemm_k<0,0,0,1><<<6 * GM128, 256, 0, stream>>>(B1b, nullptr, acr_Wqkv, acr_bqkv, (__hip_bfloat16*)Qb, T_TOK, 768, 256, 6);
  // 6. across attention (S=100)
  mha_mfma_k<112,2><<<136 * 8, 256, 0, stream>>>(Qb, (__hip_bfloat16*)ABF, 100);
  // 7. out proj + LN + un-transpose + qpos add -> TQb ; + OFFAW GEMM fused
  glnoa_k<<<GM64, 512, 0, stream>>>(ABF, acr_Wo, acr_bo, B1b, qpos, acr_ng, acr_nb,
                                    TQb, OFFAW, off_W, aw_W, off_b, aw_b, T_TOK);
  // 8. deformable sampling -> ABF bf16
  deform_k<<<T_TOK / 4, 256, 0, stream>>>(V, OFFAW, refp, (unsigned int*)ABF);
  // 9. output proj of deformable attn -> T2b bf16
  g64_k<0,1,1,0><<<dim3(4, GM64), 256, 0, stream>>>(ABF, nullptr, outp_W, outp_W, BIG, outp_b, outp_b, nullptr, nullptr, (__hip_bfloat16*)T2b, T_TOK, 256, 256, 256);
  // 10. fused gate GEMM + sigmoid + combine + LN -> B2 fp32
  gateln_k<<<GM64, 512, 0, stream>>>(TQb, T2b, gate_W, gate_b, gate_ng, gate_nb, B2, T_TOK);
  // 11. FFN up (relu, bf16 out) -> FF
  mgemm_k<1,0,0,0><<<8 * GM128, 256, 0, stream>>>(B2, nullptr, ffn_W1, ffn_b1, (__hip_bfloat16*)FF, T_TOK, 1024, 256, 8);
  // 12. FFN down + residual(B2) + clip + final LN -> out
  gln_k<2,0><<<GM64, 512, 0, stream>>>(FF, ffn_W2, ffn_b2, B2, nullptr, n2_g, n2_b, out, T_TOK, 1024);
}

// Round 12
// 460.108 us; speedup vs baseline: 1.0078x; 1.0078x over previous
//
#include <hip/hip_runtime.h>
#include <hip/hip_bf16.h>

#define NH 8
#define BS_ 8
#define NQ_ 100
#define NK_ 17
#define LQ 1700            // NQ_*NK_
#define T_TOK 13600        // BS_*LQ
#define LEN_VV 34000

typedef __attribute__((ext_vector_type(8))) short short8v;
typedef __attribute__((ext_vector_type(8))) __bf16 bf16x8;
typedef __attribute__((ext_vector_type(4))) float f32x4;

__device__ __forceinline__ short f2bf(float f){
  __hip_bfloat16 h = __float2bfloat16(f);
  return *reinterpret_cast<short*>(&h);
}
__device__ __forceinline__ float bf2f(short s){
  return __uint_as_float(((uint)(unsigned short)s) << 16);
}
__device__ __forceinline__ short8v cvt8(float4 a, float4 b){
  short8v u;
  u[0]=f2bf(a.x); u[1]=f2bf(a.y); u[2]=f2bf(a.z); u[3]=f2bf(a.w);
  u[4]=f2bf(b.x); u[5]=f2bf(b.y); u[6]=f2bf(b.z); u[7]=f2bf(b.w);
  return u;
}

// ---------------- 128x128 MFMA GEMM (fp32 or bf16 A, bf16 out via LDS epilogue) -------
template<int EPI, int ADDA, int SWZ, int INB>
__global__ __launch_bounds__(256) void mgemm_k(const void* __restrict__ Av,
                                               const float* __restrict__ A2,
                                               const float* __restrict__ W,
                                               const float* __restrict__ bias,
                                               __hip_bfloat16* __restrict__ Cb,
                                               int M, int N, int K, int nbx){
  __shared__ short sh[128 * 136];
  short* As = sh;
  short* Ws = sh + 128 * 64;
  int j;
  if (SWZ){
    int total = gridDim.x;
    int q = total >> 3, r = total & 7;
    int x = blockIdx.x & 7, k = blockIdx.x >> 3;
    j = (x < r) ? x * (q + 1) + k : r * (q + 1) + (x - r) * q + k;
  } else {
    j = blockIdx.x;
  }
  const float* A = (const float*)Av;
  const short* Ab = (const short*)Av;
  const int tid = threadIdx.x;
  const int bm = (j / nbx) * 128, bn = (j % nbx) * 128;
  const int wave = tid >> 6, lane = tid & 63;
  const int wm = (wave >> 1) * 64, wn = (wave & 1) * 64;
  const int s = tid & 7;
  const int row0 = tid >> 3;
  f32x4 acc[4][4] = {};
  const int lrow = lane & 15, lk = lane >> 4;

  float4 ra[INB ? 1 : 8], rw[8];
  short8v rab[INB ? 4 : 1];
#pragma unroll
  for (int i = 0; i < 4; i++){
    int row = row0 + i * 32;
    int gr = bm + row;
    if (INB){
      short8v z = {};
      rab[INB ? i : 0] = (gr < M) ? *(const short8v*)(Ab + (size_t)gr * K + s * 8) : z;
    } else {
      float4 z = make_float4(0.f, 0.f, 0.f, 0.f);
      if (gr < M){
        const float* p = A + (size_t)gr * K + s * 8;
        float4 x0 = ((const float4*)p)[0], x1 = ((const float4*)p)[1];
        if (ADDA){
          const float* q2 = A2 + (size_t)gr * K + s * 8;
          float4 y0 = ((const float4*)q2)[0], y1 = ((const float4*)q2)[1];
          x0.x+=y0.x; x0.y+=y0.y; x0.z+=y0.z; x0.w+=y0.w;
          x1.x+=y1.x; x1.y+=y1.y; x1.z+=y1.z; x1.w+=y1.w;
        }
        ra[INB ? 0 : (2 * i)] = x0; ra[INB ? 0 : (2 * i + 1)] = x1;
      } else { ra[INB ? 0 : (2 * i)] = z; ra[INB ? 0 : (2 * i + 1)] = z; }
    }
    const float* q = W + (size_t)(bn + row) * K + s * 8;
    rw[2 * i] = ((const float4*)q)[0]; rw[2 * i + 1] = ((const float4*)q)[1];
  }

  for (int k0 = 0; k0 < K; k0 += 64){
#pragma unroll
    for (int i = 0; i < 4; i++){
      int row = row0 + i * 32;
      int sw = ((s ^ (row & 7)) << 3) + row * 64;
      if (INB){
        *(short8v*)&As[sw] = rab[INB ? i : 0];
      } else {
        *(short8v*)&As[sw] = cvt8(ra[INB ? 0 : (2 * i)], ra[INB ? 0 : (2 * i + 1)]);
      }
      *(short8v*)&Ws[sw] = cvt8(rw[2 * i], rw[2 * i + 1]);
    }
    __syncthreads();
    if (k0 + 64 < K){
#pragma unroll
      for (int i = 0; i < 4; i++){
        int row = row0 + i * 32;
        int gr = bm + row;
        if (INB){
          short8v z = {};
          rab[INB ? i : 0] = (gr < M) ? *(const short8v*)(Ab + (size_t)gr * K + k0 + 64 + s * 8) : z;
        } else {
          float4 z = make_float4(0.f, 0.f, 0.f, 0.f);
          if (gr < M){
            const float* p = A + (size_t)gr * K + k0 + 64 + s * 8;
            float4 x0 = ((const float4*)p)[0], x1 = ((const float4*)p)[1];
            if (ADDA){
              const float* q2 = A2 + (size_t)gr * K + k0 + 64 + s * 8;
              float4 y0 = ((const float4*)q2)[0], y1 = ((const float4*)q2)[1];
              x0.x+=y0.x; x0.y+=y0.y; x0.z+=y0.z; x0.w+=y0.w;
              x1.x+=y1.x; x1.y+=y1.y; x1.z+=y1.z; x1.w+=y1.w;
            }
            ra[INB ? 0 : (2 * i)] = x0; ra[INB ? 0 : (2 * i + 1)] = x1;
          } else { ra[INB ? 0 : (2 * i)] = z; ra[INB ? 0 : (2 * i + 1)] = z; }
        }
        const float* q = W + (size_t)(bn + row) * K + k0 + 64 + s * 8;
        rw[2 * i] = ((const float4*)q)[0]; rw[2 * i + 1] = ((const float4*)q)[1];
      }
    }
#pragma unroll
    for (int ks = 0; ks < 2; ks++){
      short8v af[4], bw[4];
      int slot = ks * 4 + lk;
#pragma unroll
      for (int m = 0; m < 4; m++){
        int r = wm + m * 16 + lrow;
        af[m] = *(const short8v*)&As[r * 64 + ((slot ^ (r & 7)) << 3)];
      }
#pragma unroll
      for (int n = 0; n < 4; n++){
        int r = wn + n * 16 + lrow;
        bw[n] = *(const short8v*)&Ws[r * 64 + ((slot ^ (r & 7)) << 3)];
      }
#pragma unroll
      for (int m = 0; m < 4; m++)
#pragma unroll
        for (int n = 0; n < 4; n++)
          acc[m][n] = __builtin_amdgcn_mfma_f32_16x16x32_bf16(
              __builtin_bit_cast(bf16x8, af[m]),
              __builtin_bit_cast(bf16x8, bw[n]), acc[m][n], 0, 0, 0);
    }
    __syncthreads();
  }
  const int STR = 136;
#pragma unroll
  for (int n = 0; n < 4; n++){
    int col = wn + n * 16 + lrow;
    float bsv = bias[bn + col];
#pragma unroll
    for (int m = 0; m < 4; m++){
#pragma unroll
      for (int i = 0; i < 4; i++){
        int row = wm + m * 16 + lk * 4 + i;
        float c = acc[m][n][i] + bsv;
        if (EPI == 1) c = fmaxf(c, 0.f);
        sh[row * STR + col] = f2bf(c);
      }
    }
  }
  __syncthreads();
#pragma unroll
  for (int it = 0; it < 8; it++){
    int r = it * 16 + (tid >> 4);
    int chunk = tid & 15;
    if (bm + r < M){
      uint4 v = *(const uint4*)((const char*)sh + r * 272 + chunk * 16);
      *(uint4*)((char*)Cb + ((size_t)(bm + r) * N + bn) * 2 + chunk * 16) = v;
    }
  }
}

// ---------------- 64x64 MFMA GEMM ----------------
template<int EPI, int OUTB, int INB, int DUALA>
__global__ __launch_bounds__(256) void g64_k(const void* __restrict__ Av,
                                             const void* __restrict__ A1v,
                                             const float* __restrict__ W0,
                                             const float* __restrict__ W1,
                                             int NSPLIT,
                                             const float* __restrict__ bias0,
                                             const float* __restrict__ bias1,
                                             const float* __restrict__ RES,
                                             float* __restrict__ Cf,
                                             __hip_bfloat16* __restrict__ Cb,
                                             int M, int N, int K, int sA){
  __shared__ short sh64[2 * 64 * 64];
  short* As = sh64;
  short* Ws = sh64 + 64 * 64;
  const int tid = threadIdx.x;
  const int bn = blockIdx.x * 64, bm = blockIdx.y * 64;
  const int wave = tid >> 6, lane = tid & 63;
  const int wm = (wave >> 1) * 32, wn = (wave & 1) * 32;
  const int s = tid & 7, row0 = tid >> 3;
  const int lrow = lane & 15, lk = lane >> 4;
  f32x4 acc[2][2] = {};

  for (int k0 = 0; k0 < K; k0 += 64){
#pragma unroll
    for (int i = 0; i < 2; i++){
      int row = row0 + i * 32;
      int sw = ((s ^ (row & 7)) << 3) + row * 64;
      short8v v = {};
      int gr = bm + row;
      if (gr < M){
        if (INB){
          v = *(const short8v*)((const short*)Av + (size_t)gr * sA + k0 + s * 8);
        } else {
          const float* Ap;
          if (DUALA) Ap = (k0 < 256) ? (const float*)Av + (size_t)gr * 256 + k0
                                     : (const float*)A1v + (size_t)gr * 256 + (k0 - 256);
          else Ap = (const float*)Av + (size_t)gr * sA + k0;
          v = cvt8(((const float4*)(Ap + s * 8))[0], ((const float4*)(Ap + s * 8))[1]);
        }
      }
      *(short8v*)&As[sw] = v;
      int wr = bn + row;
      const float* Wp = (wr < NSPLIT) ? W0 + (size_t)wr * K + k0
                                      : W1 + (size_t)(wr - NSPLIT) * K + k0;
      *(short8v*)&Ws[sw] = cvt8(((const float4*)(Wp + s * 8))[0], ((const float4*)(Wp + s * 8))[1]);
    }
    __syncthreads();
#pragma unroll
    for (int ks = 0; ks < 2; ks++){
      int slot = ks * 4 + lk;
      short8v af[2], bw[2];
#pragma unroll
      for (int m = 0; m < 2; m++){
        int r = wm + m * 16 + lrow;
        af[m] = *(const short8v*)&As[r * 64 + ((slot ^ (r & 7)) << 3)];
      }
#pragma unroll
      for (int n = 0; n < 2; n++){
        int r = wn + n * 16 + lrow;
        bw[n] = *(const short8v*)&Ws[r * 64 + ((slot ^ (r & 7)) << 3)];
      }
#pragma unroll
      for (int m = 0; m < 2; m++)
#pragma unroll
        for (int n = 0; n < 2; n++)
          acc[m][n] = __builtin_amdgcn_mfma_f32_16x16x32_bf16(
              __builtin_bit_cast(bf16x8, af[m]),
              __builtin_bit_cast(bf16x8, bw[n]), acc[m][n], 0, 0, 0);
    }
    __syncthreads();
  }
  if (OUTB){
    const int STR = 72;
#pragma unroll
    for (int n = 0; n < 2; n++){
      int col = wn + n * 16 + lrow;
      int gc = bn + col;
      float bsv = (gc < NSPLIT) ? bias0[gc] : bias1[gc - NSPLIT];
#pragma unroll
      for (int m = 0; m < 2; m++){
#pragma unroll
        for (int i = 0; i < 4; i++){
          int row = wm + m * 16 + lk * 4 + i;
          float c = acc[m][n][i] + bsv;
          if (EPI == 1) c = fmaxf(c, 0.f);
          if (EPI == 2) c = 1.f / (1.f + expf(-c));
          sh64[row * STR + col] = f2bf(c);
        }
      }
    }
    __syncthreads();
#pragma unroll
    for (int it = 0; it < 2; it++){
      int r = it * 32 + (tid >> 3);
      int chunk = tid & 7;
      if (bm + r < M){
        uint4 v = *(const uint4*)((const char*)sh64 + r * 144 + chunk * 16);
        *(uint4*)((char*)Cb + ((size_t)(bm + r) * N + bn) * 2 + chunk * 16) = v;
      }
    }
  } else {
#pragma unroll
    for (int n = 0; n < 2; n++){
      int gc = bn + wn + n * 16 + lrow;
      float bsv = (gc < NSPLIT) ? bias0[gc] : bias1[gc - NSPLIT];
#pragma unroll
      for (int m = 0; m < 2; m++){
#pragma unroll
        for (int i = 0; i < 4; i++){
          int row = bm + wm + m * 16 + lk * 4 + i;
          if (row >= M) continue;
          float c = acc[m][n][i] + bsv;
          if (EPI == 1) c = fmaxf(c, 0.f);
          if (EPI == 2) c = 1.f / (1.f + expf(-c));
          if (EPI == 3) c += RES[(size_t)row * N + gc];
          Cf[(size_t)row * N + gc] = c;
        }
      }
    }
  }
}

// -------- fused GEMM (N=256) + residual + LN + permuted write; 32-row tile, 4 waves ----
// SITE 0: win — x = C + r0 + r1, LN, write transposed (b,q,k)->(b,k,q)
// SITE 2: ffn — x = C + r0, clip, LN, plain write
template<int SITE, int OUTB>
__global__ __launch_bounds__(256) void gln_k(const short* __restrict__ Abf,
                                             const float* __restrict__ W,
                                             const float* __restrict__ bias,
                                             const float* __restrict__ r0,
                                             const float* __restrict__ r1,
                                             const float* __restrict__ g,
                                             const float* __restrict__ be,
                                             void* __restrict__ outv,
                                             int M, int K){
  __shared__ short As[32 * 64];
  __shared__ short Ws[256 * 64];
  __shared__ float part[32][4][2];
  __shared__ float stats[32][2];
  const int tid = threadIdx.x;
  const int bm = blockIdx.x * 32;
  const int wave = tid >> 6, lane = tid & 63;
  const int wn = wave * 64;
  const int s = tid & 7, row0 = tid >> 3;   // 0..31
  const int lrow = lane & 15, lk = lane >> 4;
  f32x4 acc[2][4] = {};

  // prefetch k0 = 0 (A raw bf16; W converted to bf16 in regs)
  short8v pa = {};
  { int gr = bm + row0; if (gr < M) pa = *(const short8v*)(Abf + (size_t)gr * K + s * 8); }
  short8v pwb[8];
#pragma unroll
  for (int i = 0; i < 8; i++){
    const float* wp = W + (size_t)(row0 + i * 32) * K + s * 8;
    pwb[i] = cvt8(((const float4*)wp)[0], ((const float4*)wp)[1]);
  }

  for (int k0 = 0; k0 < K; k0 += 64){
    *(short8v*)&As[row0 * 64 + ((s ^ (row0 & 7)) << 3)] = pa;
#pragma unroll
    for (int i = 0; i < 8; i++){
      int row = row0 + i * 32;
      *(short8v*)&Ws[row * 64 + ((s ^ (row & 7)) << 3)] = pwb[i];
    }
    __syncthreads();
    if (k0 + 64 < K){
      int gr = bm + row0;
      pa = (short8v){};
      if (gr < M) pa = *(const short8v*)(Abf + (size_t)gr * K + k0 + 64 + s * 8);
#pragma unroll
      for (int i = 0; i < 8; i++){
        const float* wp = W + (size_t)(row0 + i * 32) * K + k0 + 64 + s * 8;
        pwb[i] = cvt8(((const float4*)wp)[0], ((const float4*)wp)[1]);
      }
    }
#pragma unroll
    for (int ks = 0; ks < 2; ks++){
      int slot = ks * 4 + lk;
      short8v af[2], bw[4];
#pragma unroll
      for (int m = 0; m < 2; m++){
        int r = m * 16 + lrow;
        af[m] = *(const short8v*)&As[r * 64 + ((slot ^ (r & 7)) << 3)];
      }
#pragma unroll
      for (int n = 0; n < 4; n++){
        int r = wn + n * 16 + lrow;
        bw[n] = *(const short8v*)&Ws[r * 64 + ((slot ^ (r & 7)) << 3)];
      }
#pragma unroll
      for (int m = 0; m < 2; m++)
#pragma unroll
        for (int n = 0; n < 4; n++)
          acc[m][n] = __builtin_amdgcn_mfma_f32_16x16x32_bf16(
              __builtin_bit_cast(bf16x8, af[m]),
              __builtin_bit_cast(bf16x8, bw[n]), acc[m][n], 0, 0, 0);
    }
    __syncthreads();
  }

#pragma unroll
  for (int m = 0; m < 2; m++){
#pragma unroll
    for (int i = 0; i < 4; i++){
      int row = m * 16 + lk * 4 + i;
      int grow = bm + row;
      float s1 = 0.f, s2 = 0.f;
      if (grow < M){
#pragma unroll
        for (int n = 0; n < 4; n++){
          int col = wn + n * 16 + lrow;
          float x = acc[m][n][i] + bias[col] + r0[(size_t)grow * 256 + col];
          if (SITE == 0) x += r1[(size_t)grow * 256 + col];
          if (SITE == 2) x = fminf(fmaxf(x, -65504.f), 65504.f);
          acc[m][n][i] = x;
          s1 += x; s2 += x * x;
        }
      }
#pragma unroll
      for (int msk = 1; msk <= 8; msk <<= 1){
        s1 += __shfl_xor(s1, msk, 64);
        s2 += __shfl_xor(s2, msk, 64);
      }
      if (lrow == 0){ part[row][wave][0] = s1; part[row][wave][1] = s2; }
    }
  }
  __syncthreads();
  if (tid < 32){
    float s1 = part[tid][0][0] + part[tid][1][0] + part[tid][2][0] + part[tid][3][0];
    float s2 = part[tid][0][1] + part[tid][1][1] + part[tid][2][1] + part[tid][3][1];
    float mean = s1 * (1.f / 256.f);
    float var = s2 * (1.f / 256.f) - mean * mean;
    stats[tid][0] = mean;
    stats[tid][1] = rsqrtf(fmaxf(var, 0.f) + 1e-5f);
  }
  __syncthreads();
#pragma unroll
  for (int m = 0; m < 2; m++){
#pragma unroll
    for (int i = 0; i < 4; i++){
      int row = m * 16 + lk * 4 + i;
      int grow = bm + row;
      if (grow >= M) continue;
      float mean = stats[row][0], rstd = stats[row][1];
      size_t orow = grow;
      if (SITE == 0){
        int bi = grow / LQ; int rem = grow % LQ; int q = rem / NK_; int kk = rem % NK_;
        orow = (size_t)bi * LQ + kk * NQ_ + q;
      }
#pragma unroll
      for (int n = 0; n < 4; n++){
        int col = wn + n * 16 + lrow;
        float o = (acc[m][n][i] - mean) * rstd * g[col] + be[col];
        if (OUTB) ((short*)outv)[orow * 256 + col] = f2bf(o);
        else      ((float*)outv)[orow * 256 + col] = o;
      }
    }
  }
}

// ---- fused acr out-proj + LN + qpos add + OFFAW GEMM; 32-row tile, 4 waves ----
__global__ __launch_bounds__(256) void glnoa_k(const short* __restrict__ Abf,
                                               const float* __restrict__ W,
                                               const float* __restrict__ bias,
                                               const short* __restrict__ r0b,
                                               const float* __restrict__ qpos,
                                               const float* __restrict__ g,
                                               const float* __restrict__ be,
                                               short* __restrict__ TQout,
                                               float* __restrict__ OFFAW,
                                               const float* __restrict__ off_W,
                                               const float* __restrict__ aw_W,
                                               const float* __restrict__ off_b,
                                               const float* __restrict__ aw_b,
                                               int M){
  __shared__ short smem[32 * 256 + 384 * 64];   // As2 | Ws2 union (64 KB)
  __shared__ float part[32][4][2];
  __shared__ float stats[32][2];
  short* As1 = smem;                    // [32][64] phase 1
  short* Ws1 = smem + 32 * 64;          // [256][64] phase 1
  short* As2 = smem;                    // [32][256] phase 2
  short* Ws2 = smem + 32 * 256;         // [384][64] phase 2
  const int K = 256;
  const int tid = threadIdx.x;
  const int bm = blockIdx.x * 32;
  const int wave = tid >> 6, lane = tid & 63;
  const int wn = wave * 64;
  const int s = tid & 7, row0 = tid >> 3;
  const int lrow = lane & 15, lk = lane >> 4;
  f32x4 acc[2][4] = {};

  short8v pa = {};
  { int gr = bm + row0; if (gr < M) pa = *(const short8v*)(Abf + (size_t)gr * K + s * 8); }
  short8v pwb[8];
#pragma unroll
  for (int i = 0; i < 8; i++){
    const float* wp = W + (size_t)(row0 + i * 32) * K + s * 8;
    pwb[i] = cvt8(((const float4*)wp)[0], ((const float4*)wp)[1]);
  }
  for (int k0 = 0; k0 < K; k0 += 64){
    *(short8v*)&As1[row0 * 64 + ((s ^ (row0 & 7)) << 3)] = pa;
#pragma unroll
    for (int i = 0; i < 8; i++){
      int row = row0 + i * 32;
      *(short8v*)&Ws1[row * 64 + ((s ^ (row & 7)) << 3)] = pwb[i];
    }
    __syncthreads();
    if (k0 + 64 < K){
      int gr = bm + row0;
      pa = (short8v){};
      if (gr < M) pa = *(const short8v*)(Abf + (size_t)gr * K + k0 + 64 + s * 8);
#pragma unroll
      for (int i = 0; i < 8; i++){
        const float* wp = W + (size_t)(row0 + i * 32) * K + k0 + 64 + s * 8;
        pwb[i] = cvt8(((const float4*)wp)[0], ((const float4*)wp)[1]);
      }
    }
#pragma unroll
    for (int ks = 0; ks < 2; ks++){
      int slot = ks * 4 + lk;
      short8v af[2], bw[4];
#pragma unroll
      for (int m = 0; m < 2; m++){
        int r = m * 16 + lrow;
        af[m] = *(const short8v*)&As1[r * 64 + ((slot ^ (r & 7)) << 3)];
      }
#pragma unroll
      for (int n = 0; n < 4; n++){
        int r = wn + n * 16 + lrow;
        bw[n] = *(const short8v*)&Ws1[r * 64 + ((slot ^ (r & 7)) << 3)];
      }
#pragma unroll
      for (int m = 0; m < 2; m++)
#pragma unroll
        for (int n = 0; n < 4; n++)
          acc[m][n] = __builtin_amdgcn_mfma_f32_16x16x32_bf16(
              __builtin_bit_cast(bf16x8, af[m]),
              __builtin_bit_cast(bf16x8, bw[n]), acc[m][n], 0, 0, 0);
    }
    __syncthreads();
  }
  // residual (bf16) + partial sums
#pragma unroll
  for (int m = 0; m < 2; m++){
#pragma unroll
    for (int i = 0; i < 4; i++){
      int row = m * 16 + lk * 4 + i;
      int grow = bm + row;
      float s1 = 0.f, s2 = 0.f;
      if (grow < M){
#pragma unroll
        for (int n = 0; n < 4; n++){
          int col = wn + n * 16 + lrow;
          float x = acc[m][n][i] + bias[col] + bf2f(r0b[(size_t)grow * 256 + col]);
          acc[m][n][i] = x;
          s1 += x; s2 += x * x;
        }
      }
#pragma unroll
      for (int msk = 1; msk <= 8; msk <<= 1){
        s1 += __shfl_xor(s1, msk, 64);
        s2 += __shfl_xor(s2, msk, 64);
      }
      if (lrow == 0){ part[row][wave][0] = s1; part[row][wave][1] = s2; }
    }
  }
  __syncthreads();
  if (tid < 32){
    float s1 = part[tid][0][0] + part[tid][1][0] + part[tid][2][0] + part[tid][3][0];
    float s2 = part[tid][0][1] + part[tid][1][1] + part[tid][2][1] + part[tid][3][1];
    float mean = s1 * (1.f / 256.f);
    float var = s2 * (1.f / 256.f) - mean * mean;
    stats[tid][0] = mean;
    stats[tid][1] = rsqrtf(fmaxf(var, 0.f) + 1e-5f);
  }
  __syncthreads();
  // normalize, add qpos, write TQout + stage TQ into As2 (bf16, swizzled)
#pragma unroll
  for (int m = 0; m < 2; m++){
#pragma unroll
    for (int i = 0; i < 4; i++){
      int row = m * 16 + lk * 4 + i;
      int grow = bm + row;
      float mean = stats[row][0], rstd = stats[row][1];
      size_t orow = 0;
      if (grow < M){
        int bi = grow / LQ; int rem = grow % LQ; int kk = rem / NQ_; int q = rem % NQ_;
        orow = (size_t)bi * LQ + q * NK_ + kk;
      }
#pragma unroll
      for (int n = 0; n < 4; n++){
        int col = wn + n * 16 + lrow;
        float tq = 0.f;
        if (grow < M){
          float o = (acc[m][n][i] - mean) * rstd * g[col] + be[col];
          tq = o + qpos[orow * 256 + col];
          TQout[orow * 256 + col] = f2bf(tq);
        }
        As2[row * 256 + ((((col >> 3) ^ (row & 7)) << 3) + (col & 7))] = f2bf(tq);
      }
    }
  }
  __syncthreads();
  // phase 2: OFFAW = TQ @ [off_W|aw_W]^T  (N=384, K=256); wave covers 96 cols
  const int wn2 = wave * 96;
  f32x4 acc2[2][6] = {};
  for (int k0 = 0; k0 < 256; k0 += 64){
#pragma unroll
    for (int it = 0; it < 12; it++){
      int wr = row0 + it * 32;   // 0..383
      const float* Wp = (wr < 256) ? off_W + (size_t)wr * 256 + k0
                                   : aw_W + (size_t)(wr - 256) * 256 + k0;
      *(short8v*)&Ws2[wr * 64 + ((s ^ (wr & 7)) << 3)] =
          cvt8(((const float4*)(Wp + s * 8))[0], ((const float4*)(Wp + s * 8))[1]);
    }
    __syncthreads();
#pragma unroll
    for (int ks = 0; ks < 2; ks++){
      int slotl = ks * 4 + lk;
      int slotg = (k0 >> 3) + slotl;
      short8v af[2], bw[6];
#pragma unroll
      for (int m = 0; m < 2; m++){
        int r = m * 16 + lrow;
        af[m] = *(const short8v*)&As2[r * 256 + ((slotg ^ (r & 7)) << 3)];
      }
#pragma unroll
      for (int n = 0; n < 6; n++){
        int r = wn2 + n * 16 + lrow;
        bw[n] = *(const short8v*)&Ws2[r * 64 + ((slotl ^ (r & 7)) << 3)];
      }
#pragma unroll
      for (int m = 0; m < 2; m++)
#pragma unroll
        for (int n = 0; n < 6; n++)
          acc2[m][n] = __builtin_amdgcn_mfma_f32_16x16x32_bf16(
              __builtin_bit_cast(bf16x8, af[m]),
              __builtin_bit_cast(bf16x8, bw[n]), acc2[m][n], 0, 0, 0);
    }
    __syncthreads();
  }
#pragma unroll
  for (int m = 0; m < 2; m++){
#pragma unroll
    for (int i = 0; i < 4; i++){
      int row = m * 16 + lk * 4 + i;
      int grow = bm + row;
      if (grow >= M) continue;
      int bi = grow / LQ; int rem = grow % LQ; int kk = rem / NQ_; int q = rem % NQ_;
      size_t orow = (size_t)bi * LQ + q * NK_ + kk;
#pragma unroll
      for (int n = 0; n < 6; n++){
        int col = wn2 + n * 16 + lrow;
        float c = acc2[m][n][i] + ((col < 256) ? off_b[col] : aw_b[col - 256]);
        OFFAW[orow * 384 + col] = c;
      }
    }
  }
}

// ---- fused gate GEMM (K=512) + sigmoid + combine + LN; 32-row tile, 4 waves ----
__global__ __launch_bounds__(256) void gateln_k(const short* __restrict__ TQ,
                                                const short* __restrict__ T2,
                                                const float* __restrict__ W,
                                                const float* __restrict__ bias,
                                                const float* __restrict__ g,
                                                const float* __restrict__ be,
                                                float* __restrict__ out, int M){
  __shared__ short sh[32 * 64 + 512 * 64];   // As | Ws ; reused as gbuf[32][520]
  short* As = sh;
  short* Ws = sh + 32 * 64;
  const int tid = threadIdx.x;
  const int bm = blockIdx.x * 32;
  const int wave = tid >> 6, lane = tid & 63;
  const int wn = wave * 128;
  const int s = tid & 7, row0 = tid >> 3;
  const int lrow = lane & 15, lk = lane >> 4;
  f32x4 acc[2][8] = {};

  for (int k0 = 0; k0 < 512; k0 += 64){
    {
      short8v v = {};
      int gr = bm + row0;
      if (gr < M){
        v = (k0 < 256) ? *(const short8v*)(TQ + (size_t)gr * 256 + k0 + s * 8)
                       : *(const short8v*)(T2 + (size_t)gr * 256 + (k0 - 256) + s * 8);
      }
      *(short8v*)&As[row0 * 64 + ((s ^ (row0 & 7)) << 3)] = v;
    }
#pragma unroll
    for (int i = 0; i < 16; i++){
      int row = row0 + i * 32;
      const float* wp = W + (size_t)row * 512 + k0 + s * 8;
      *(short8v*)&Ws[row * 64 + ((s ^ (row & 7)) << 3)] =
          cvt8(((const float4*)wp)[0], ((const float4*)wp)[1]);
    }
    __syncthreads();
#pragma unroll
    for (int ks = 0; ks < 2; ks++){
      int slot = ks * 4 + lk;
      short8v af[2], bw[8];
#pragma unroll
      for (int m = 0; m < 2; m++){
        int r = m * 16 + lrow;
        af[m] = *(const short8v*)&As[r * 64 + ((slot ^ (r & 7)) << 3)];
      }
#pragma unroll
      for (int n = 0; n < 8; n++){
        int r = wn + n * 16 + lrow;
        bw[n] = *(const short8v*)&Ws[r * 64 + ((slot ^ (r & 7)) << 3)];
      }
#pragma unroll
      for (int m = 0; m < 2; m++)
#pragma unroll
        for (int n = 0; n < 8; n++)
          acc[m][n] = __builtin_amdgcn_mfma_f32_16x16x32_bf16(
              __builtin_bit_cast(bf16x8, af[m]),
              __builtin_bit_cast(bf16x8, bw[n]), acc[m][n], 0, 0, 0);
    }
    __syncthreads();
  }
  short* gb = sh;
  const int GSTR = 520;
#pragma unroll
  for (int n = 0; n < 8; n++){
    int col = wn + n * 16 + lrow;
    float bsv = bias[col];
#pragma unroll
    for (int m = 0; m < 2; m++){
#pragma unroll
      for (int i = 0; i < 4; i++){
        int row = m * 16 + lk * 4 + i;
        float c = acc[m][n][i] + bsv;
        gb[row * GSTR + col] = f2bf(1.f / (1.f + __expf(-c)));
      }
    }
  }
  __syncthreads();
  {
    int row = tid >> 3, cg = tid & 7;
    int grow = bm + row;
    float x[32];
    float s1 = 0.f, s2 = 0.f;
    if (grow < M){
#pragma unroll
      for (int jv = 0; jv < 4; jv++){
        int c0 = cg * 32 + jv * 8;
        short8v aqv = *(const short8v*)(TQ + (size_t)grow * 256 + c0);
        short8v t2v = *(const short8v*)(T2 + (size_t)grow * 256 + c0);
#pragma unroll
        for (int jj = 0; jj < 8; jj++){
          float g1 = bf2f(gb[row * GSTR + c0 + jj]);
          float g2 = bf2f(gb[row * GSTR + 256 + c0 + jj]);
          float xv = g1 * bf2f(aqv[jj]) + g2 * bf2f(t2v[jj]);
          x[jv * 8 + jj] = xv; s1 += xv; s2 += xv * xv;
        }
      }
    }
    s1 += __shfl_xor(s1, 1, 64); s2 += __shfl_xor(s2, 1, 64);
    s1 += __shfl_xor(s1, 2, 64); s2 += __shfl_xor(s2, 2, 64);
    s1 += __shfl_xor(s1, 4, 64); s2 += __shfl_xor(s2, 4, 64);
    float mean = s1 * (1.f / 256.f);
    float var = s2 * (1.f / 256.f) - mean * mean;
    float rstd = rsqrtf(fmaxf(var, 0.f) + 1e-5f);
    if (grow < M){
#pragma unroll
      for (int jv = 0; jv < 4; jv++){
        int c0 = cg * 32 + jv * 8;
        float4 o0, o1;
#pragma unroll
        for (int jj = 0; jj < 8; jj++){
          int c = c0 + jj;
          float o = (x[jv * 8 + jj] - mean) * rstd * g[c] + be[c];
          if (jj < 4) ((float*)&o0)[jj] = o; else ((float*)&o1)[jj - 4] = o;
        }
        *(float4*)(out + (size_t)grow * 256 + c0) = o0;
        *(float4*)(out + (size_t)grow * 256 + c0 + 4) = o1;
      }
    }
  }
}

// ---------------- MFMA MHA ----------------
template<int TP, int NSPL>
__global__ __launch_bounds__(256) void mha_mfma_k(const short* __restrict__ qkv,
                                                  __hip_bfloat16* __restrict__ out, int S){
  constexpr int MT = TP / 16;
  constexpr int KSTEPS = (TP + 31) / 32;
  constexpr int KS32 = KSTEPS * 32;
  constexpr int VSTRB = (KS32 == 128) ? 256 : 128;
  constexpr int CH = (MT + NSPL - 1) / NSPL;
  __shared__ short QK[2][TP][64];
  __shared__ short Vt[2][32][VSTRB / 2];
  __shared__ float Sc[2][16][128];
  __shared__ float rinv[2][16];

  const int tid = threadIdx.x;
  const int bid = blockIdx.x;
  const int batch = bid / (4 * NSPL);
  const int rem = bid % (4 * NSPL);
  const int hp = rem / NSPL;
  const int half = rem % NSPL;
  const int mtlo = half * CH;
  const int mthi = (mtlo + CH < MT) ? (mtlo + CH) : MT;
  const int wave = tid >> 6, lane = tid & 63;
  const int hh = wave >> 1, wsub = wave & 1;
  const int lrow = lane & 15, lk = lane >> 4;
  const float scale = 0.17677669529663687f;
  const size_t qbase = (size_t)batch * S * 768;

  for (int idx = tid; idx < 2 * TP * 4; idx += 256){
    int h2 = idx >= TP * 4;
    int rm = idx - h2 * TP * 4;
    int j = rm >> 2, s = rm & 3;
    int h = hp * 2 + h2;
    short8v qv = {}, kv = {};
    if (j < S){
      const short* p = qkv + qbase + (size_t)j * 768 + h * 32 + s * 8;
      qv = *(const short8v*)p;
      kv = *(const short8v*)(p + 256);
    }
    *(short8v*)&QK[h2][j][(s ^ (j & 7)) << 3] = qv;
    *(short8v*)&QK[h2][j][((s + 4) ^ (j & 7)) << 3] = kv;
  }
  for (int idx = tid; idx < 2 * KS32 * 4; idx += 256){
    int h2 = idx >= KS32 * 4;
    int rm = idx - h2 * KS32 * 4;
    int j = rm >> 2, e8 = rm & 3;
    int h = hp * 2 + h2;
    short8v v = {};
    if (j < S) v = *(const short8v*)(qkv + qbase + (size_t)j * 768 + h * 32 + 512 + e8 * 8);
#pragma unroll
    for (int c = 0; c < 8; c++){
      int e = e8 * 8 + c;
      char* pb = (char*)&Vt[h2][0][0] + e * VSTRB + (((j >> 3) ^ (e & 7)) << 4) + ((j & 7) << 1);
      *(short*)pb = v[c];
    }
  }
  __syncthreads();

  for (int mt = mtlo; mt < mthi; mt++){
    for (int nt = wsub; nt < MT; nt += 2){
      int ar = mt * 16 + lrow;
      short8v aq = *(const short8v*)&QK[hh][ar][(lk ^ (ar & 7)) << 3];
      int br = nt * 16 + lrow;
      short8v bk = *(const short8v*)&QK[hh][br][((lk + 4) ^ (br & 7)) << 3];
      f32x4 z = {};
      f32x4 d = __builtin_amdgcn_mfma_f32_16x16x32_bf16(
          __builtin_bit_cast(bf16x8, aq), __builtin_bit_cast(bf16x8, bk), z, 0, 0, 0);
#pragma unroll
      for (int i = 0; i < 4; i++){
        int rr = lk * 4 + i;
        int c = nt * 16 + lrow;
        Sc[hh][rr][(((c >> 2) ^ (rr & 7)) << 2) + (c & 3)] = d[i] * scale;
      }
    }
    __syncthreads();
    if (wsub == 0){
      int rr = lane >> 2, p = lane & 3;
      int grow = mt * 16 + rr;
      int Seff = (grow < S) ? S : 0;
      float mx = -1e30f;
#pragma unroll
      for (int m = 0; m < KSTEPS; m++){
        int j = p + 4 * m;
#pragma unroll
        for (int hf = 0; hf < 2; hf++){
          int ls = 2 * j + hf;
          float4 v = *(const float4*)&Sc[hh][rr][(ls ^ (rr & 7)) << 2];
          int c0 = ls * 4;
          mx = fmaxf(mx, (c0 + 0 < Seff) ? v.x : -1e30f);
          mx = fmaxf(mx, (c0 + 1 < Seff) ? v.y : -1e30f);
          mx = fmaxf(mx, (c0 + 2 < Seff) ? v.z : -1e30f);
          mx = fmaxf(mx, (c0 + 3 < Seff) ? v.w : -1e30f);
        }
      }
      mx = fmaxf(mx, __shfl_xor(mx, 1, 64));
      mx = fmaxf(mx, __shfl_xor(mx, 2, 64));
      float sum = 0.f;
#pragma unroll
      for (int m = 0; m < KSTEPS; m++){
        int j = p + 4 * m;
        float ev[8];
#pragma unroll
        for (int hf = 0; hf < 2; hf++){
          int ls = 2 * j + hf;
          float4 v = *(const float4*)&Sc[hh][rr][(ls ^ (rr & 7)) << 2];
          int c0 = ls * 4;
          ev[hf * 4 + 0] = (c0 + 0 < Seff) ? __expf(v.x - mx) : 0.f;
          ev[hf * 4 + 1] = (c0 + 1 < Seff) ? __expf(v.y - mx) : 0.f;
          ev[hf * 4 + 2] = (c0 + 2 < Seff) ? __expf(v.z - mx) : 0.f;
          ev[hf * 4 + 3] = (c0 + 3 < Seff) ? __expf(v.w - mx) : 0.f;
        }
        short8v pb;
#pragma unroll
        for (int q2 = 0; q2 < 8; q2++){ pb[q2] = f2bf(ev[q2]); sum += ev[q2]; }
        *(short8v*)((char*)&Sc[hh][rr][0] + ((j ^ (rr & 7)) << 4)) = pb;
      }
      sum += __shfl_xor(sum, 1, 64);
      sum += __shfl_xor(sum, 2, 64);
      if (p == 0) rinv[hh][rr] = (sum > 0.f) ? 1.f / sum : 0.f;
    }
    __syncthreads();
    {
      int nt2 = wsub;
      f32x4 acc = {};
#pragma unroll
      for (int ks = 0; ks < KSTEPS; ks++){
        int slot = ks * 4 + lk;
        short8v ap = *(const short8v*)((const char*)&Sc[hh][lrow][0] + ((slot ^ (lrow & 7)) << 4));
        int e = nt2 * 16 + lrow;
        short8v bv = *(const short8v*)((const char*)&Vt[hh][0][0] + e * VSTRB + ((slot ^ (e & 7)) << 4));
        acc = __builtin_amdgcn_mfma_f32_16x16x32_bf16(
            __builtin_bit_cast(bf16x8, ap), __builtin_bit_cast(bf16x8, bv), acc, 0, 0, 0);
      }
      int h = hp * 2 + hh;
#pragma unroll
      for (int i = 0; i < 4; i++){
        int row = mt * 16 + lk * 4 + i;
        if (row < S){
          float rv = rinv[hh][lk * 4 + i];
          out[((size_t)batch * S + row) * 256 + h * 32 + nt2 * 16 + lrow] =
              __float2bfloat16(acc[i] * rv);
        }
      }
    }
    __syncthreads();
  }
}

// ---------------- deformable sampling, two-phase; bf16 out ----------------
__global__ __launch_bounds__(256) void deform_k(const __hip_bfloat16* __restrict__ val,
                                                const float* __restrict__ offaw,
                                                const float* __restrict__ ref,
                                                unsigned int* __restrict__ outb){
  __shared__ uint2 meta[32][16][4];
  const int tid = threadIdx.x;
  const int t0 = blockIdx.x * 4;
  {
    int g = tid >> 3;
    int pair = tid & 7;
    int lt = g >> 3, h = g & 7;
    int t = t0 + lt;
    int b = t / LQ;
    int p0 = pair * 2;
    int l = p0 >> 2;
    const int starts[4] = {0, 25600, 32000, 33600};
    const int HS[4] = {160, 80, 40, 20};
    int w = HS[l];
    const float* ap = offaw + (size_t)t * 384 + 256 + h * 16;
    float a0 = ap[p0];
    float a1 = ap[p0 + 1];
    float mx = fmaxf(a0, a1);
#pragma unroll
    for (int m = 1; m <= 4; m <<= 1) mx = fmaxf(mx, __shfl_xor(mx, m, 64));
    float e0 = expf(a0 - mx), e1 = expf(a1 - mx);
    float s = e0 + e1;
#pragma unroll
    for (int m = 1; m <= 4; m <<= 1) s += __shfl_xor(s, m, 64);
    float inv = 1.f / s;
    float rx = ref[((size_t)t * 4 + l) * 2 + 0];
    float ry = ref[((size_t)t * 4 + l) * 2 + 1];
    float4 ov = *(const float4*)(offaw + (size_t)t * 384 + h * 32 + l * 8 + p0 * 2);
    int vbase = (b * LEN_VV + starts[l]) * 128 + h * 16;
#pragma unroll
    for (int pp = 0; pp < 2; pp++){
      float wgt = (pp ? e1 : e0) * inv;
      float px = rx * w + (pp ? ov.z : ov.x) - 0.5f;
      float py = ry * w + (pp ? ov.w : ov.y) - 0.5f;
      float x0f = floorf(px), y0f = floorf(py);
      float lx = px - x0f, ly = py - y0f;
      int x0 = (int)x0f, y0 = (int)y0f;
#pragma unroll
      for (int c = 0; c < 4; c++){
        int dx = c & 1, dy = c >> 1;
        int xi = x0 + dx, yi = y0 + dy;
        bool ok = (xi >= 0) & (xi < w) & (yi >= 0) & (yi < w);
        float cw = ok ? wgt * (dx ? lx : 1.f - lx) * (dy ? ly : 1.f - ly) : 0.f;
        uint idx = ok ? (uint)(vbase + (yi * w + xi) * 128) : 0u;
        uint2 m2; m2.x = idx; m2.y = __float_as_uint(cw);
        meta[g][p0 + pp][c] = m2;
      }
    }
  }
  __syncthreads();
  const uint2* V2 = (const uint2*)val;
  int sg = tid >> 3, lane8 = tid & 7;
  int lt = sg >> 3, h = sg & 7;
  int t = t0 + lt;
  float a0 = 0.f, a1 = 0.f, a2 = 0.f, a3 = 0.f;
#pragma unroll 4
  for (int c = 0; c < 64; c++){
    uint2 mw = meta[sg][c >> 2][c & 3];
    float wv = __uint_as_float(mw.y);
    uint2 v = V2[(size_t)(mw.x >> 1) + lane8];
    a0 += wv * __uint_as_float(v.x << 16);
    a1 += wv * __uint_as_float(v.x & 0xffff0000u);
    a2 += wv * __uint_as_float(v.y << 16);
    a3 += wv * __uint_as_float(v.y & 0xffff0000u);
  }
  uint2 u;
  u.x = ((uint)(unsigned short)f2bf(a1) << 16) | (uint)(unsigned short)f2bf(a0);
  u.y = ((uint)(unsigned short)f2bf(a3) << 16) | (uint)(unsigned short)f2bf(a2);
  ((uint2*)outb)[((size_t)t * 256 + h * 32) / 4 + lane8] = u;
}

extern "C" void kernel_launch(void* const* d_in, const int* in_sizes, int n_in,
                              void* d_out, int out_size, void* d_ws, size_t ws_size,
                              hipStream_t stream){
  const float* tgt_pose = (const float*)d_in[0];
  const float* qpos     = (const float*)d_in[1];
  const float* refp     = (const float*)d_in[2];
  const float* memory   = (const float*)d_in[3];
  const float* win_Wqkv = (const float*)d_in[4];
  const float* win_bqkv = (const float*)d_in[5];
  const float* win_Wo   = (const float*)d_in[6];
  const float* win_bo   = (const float*)d_in[7];
  const float* win_ng   = (const float*)d_in[8];
  const float* win_nb   = (const float*)d_in[9];
  const float* acr_Wqkv = (const float*)d_in[10];
  const float* acr_bqkv = (const float*)d_in[11];
  const float* acr_Wo   = (const float*)d_in[12];
  const float* acr_bo   = (const float*)d_in[13];
  const float* acr_ng   = (const float*)d_in[14];
  const float* acr_nb   = (const float*)d_in[15];
  const float* off_W    = (const float*)d_in[16];
  const float* off_b    = (const float*)d_in[17];
  const float* aw_W     = (const float*)d_in[18];
  const float* aw_b     = (const float*)d_in[19];
  const float* val_W    = (const float*)d_in[20];
  const float* val_b    = (const float*)d_in[21];
  const float* outp_W   = (const float*)d_in[22];
  const float* outp_b   = (const float*)d_in[23];
  const float* gate_W   = (const float*)d_in[24];
  const float* gate_b   = (const float*)d_in[25];
  const float* gate_ng  = (const float*)d_in[26];
  const float* gate_nb  = (const float*)d_in[27];
  const float* ffn_W1   = (const float*)d_in[28];
  const float* ffn_b1   = (const float*)d_in[29];
  const float* ffn_W2   = (const float*)d_in[30];
  const float* ffn_b2   = (const float*)d_in[31];
  const float* n2_g     = (const float*)d_in[32];
  const float* n2_b     = (const float*)d_in[33];

  float* out = (float*)d_out;
  char* ws = (char*)d_ws;
  const size_t TB = (size_t)T_TOK * 256 * 4;
  float* B2 = (float*)(ws);                                 // fp32 tgt3
  char* p = ws + TB;
  short* B1b = (short*)p;  p += (size_t)T_TOK * 256 * 2;    // bf16 tgt1 (b,k,q)
  short* Qb  = (short*)p;  p += (size_t)T_TOK * 768 * 2;    // bf16 qkv
  short* ABF = (short*)p;  p += (size_t)T_TOK * 256 * 2;    // bf16 attn/deform out
  short* TQb = (short*)p;  p += (size_t)T_TOK * 256 * 2;    // bf16 tgt_q
  short* T2b = (short*)p;  p += (size_t)T_TOK * 256 * 2;    // bf16 t2
  float* OFFAW = (float*)p; p += (size_t)T_TOK * 384 * 4;   // off|aw logits
  char* Vregion = p;
  __hip_bfloat16* V = (__hip_bfloat16*)Vregion;             // 139 MB
  short* FF = (short*)Vregion;                              // overlay (V dead after deform)

  const int GM128 = (T_TOK + 127) / 128;   // 107
  const int GM64  = (T_TOK + 63) / 64;     // 213
  const int GM32  = (T_TOK + 31) / 32;     // 425
  const int BIG = 1 << 30;

  // 1. value proj (XCD-swizzled) -> V bf16
  mgemm_k<0,0,1,0><<<2 * 2125, 256, 0, stream>>>(memory, nullptr, val_W, val_b, V, BS_ * LEN_VV, 256, 256, 2);
  // 2. within qkv (A = tgt_pose + qpos fused) -> Qb
  mgemm_k<0,1,0,0><<<6 * GM128, 256, 0, stream>>>(tgt_pose, qpos, win_Wqkv, win_bqkv, (__hip_bfloat16*)Qb, T_TOK, 768, 256, 6);
  // 3. within attention (S=17)
  mha_mfma_k<32,1><<<800 * 4, 256, 0, stream>>>(Qb, (__hip_bfloat16*)ABF, 17);
  // 4. out proj + LN(tgt_pose+qpos+C) + transpose write -> B1b bf16 (b,k,q)
  gln_k<0,1><<<GM32, 256, 0, stream>>>(ABF, win_Wo, win_bo, tgt_pose, qpos, win_ng, win_nb, B1b, T_TOK, 256);
  // 5. across qkv (A = B1b bf16) -> Qb
  mgemm_k<0,0,0,1><<<6 * GM128, 256, 0, stream>>>(B1b, nullptr, acr_Wqkv, acr_bqkv, (__hip_bfloat16*)Qb, T_TOK, 768, 256, 6);
  // 6. across attention (S=100)
  mha_mfma_k<112,2><<<136 * 8, 256, 0, stream>>>(Qb, (__hip_bfloat16*)ABF, 100);
  // 7. out proj + LN + un-transpose + qpos add -> TQb ; + OFFAW GEMM fused
  glnoa_k<<<GM32, 256, 0, stream>>>(ABF, acr_Wo, acr_bo, B1b, qpos, acr_ng, acr_nb,
                                    TQb, OFFAW, off_W, aw_W, off_b, aw_b, T_TOK);
  // 8. deformable sampling -> ABF bf16
  deform_k<<<T_TOK / 4, 256, 0, stream>>>(V, OFFAW, refp, (unsigned int*)ABF);
  // 9. output proj of deformable attn -> T2b bf16
  g64_k<0,1,1,0><<<dim3(4, GM64), 256, 0, stream>>>(ABF, nullptr, outp_W, outp_W, BIG, outp_b, outp_b, nullptr, nullptr, (__hip_bfloat16*)T2b, T_TOK, 256, 256, 256);
  // 10. fused gate GEMM + sigmoid + combine + LN -> B2 fp32
  gateln_k<<<GM32, 256, 0, stream>>>(TQb, T2b, gate_W, gate_b, gate_ng, gate_nb, B2, T_TOK);
  // 11. FFN up (relu, bf16 out) -> FF
  mgemm_k<1,0,0,0><<<8 * GM128, 256, 0, stream>>>(B2, nullptr, ffn_W1, ffn_b1, (__hip_bfloat16*)FF, T_TOK, 1024, 256, 8);
  // 12. FFN down + residual(B2) + clip + final LN -> out
  gln_k<2,0><<<GM32, 256, 0, stream>>>(FF, ffn_W2, ffn_b2, B2, nullptr, n2_g, n2_b, out, T_TOK, 1024);
}

// Round 13
// 459.641 us; speedup vs baseline: 1.0088x; 1.0010x over previous
//
#include <hip/hip_runtime.h>
#include <hip/hip_bf16.h>

#define NH 8
#define BS_ 8
#define NQ_ 100
#define NK_ 17
#define LQ 1700            // NQ_*NK_
#define T_TOK 13600        // BS_*LQ
#define LEN_VV 34000

typedef __attribute__((ext_vector_type(8))) short short8v;
typedef __attribute__((ext_vector_type(8))) __bf16 bf16x8;
typedef __attribute__((ext_vector_type(4))) float f32x4;

__device__ __forceinline__ short f2bf(float f){
  __hip_bfloat16 h = __float2bfloat16(f);
  return *reinterpret_cast<short*>(&h);
}
__device__ __forceinline__ float bf2f(short s){
  return __uint_as_float(((uint)(unsigned short)s) << 16);
}
__device__ __forceinline__ short8v cvt8(float4 a, float4 b){
  short8v u;
  u[0]=f2bf(a.x); u[1]=f2bf(a.y); u[2]=f2bf(a.z); u[3]=f2bf(a.w);
  u[4]=f2bf(b.x); u[5]=f2bf(b.y); u[6]=f2bf(b.z); u[7]=f2bf(b.w);
  return u;
}

// ---------------- 128x128 MFMA GEMM (fp32 or bf16 A, bf16 out via LDS epilogue) -------
// No register double-buffer: low VGPR -> 4 blocks/CU for HBM-latency hiding.
template<int EPI, int ADDA, int SWZ, int INB>
__global__ __launch_bounds__(256, 4) void mgemm_k(const void* __restrict__ Av,
                                                  const float* __restrict__ A2,
                                                  const float* __restrict__ W,
                                                  const float* __restrict__ bias,
                                                  __hip_bfloat16* __restrict__ Cb,
                                                  int M, int N, int K, int nbx){
  __shared__ short sh[128 * 136];
  short* As = sh;
  short* Ws = sh + 128 * 64;
  int j;
  if (SWZ){
    int total = gridDim.x;
    int q = total >> 3, r = total & 7;
    int x = blockIdx.x & 7, k = blockIdx.x >> 3;
    j = (x < r) ? x * (q + 1) + k : r * (q + 1) + (x - r) * q + k;
  } else {
    j = blockIdx.x;
  }
  const float* A = (const float*)Av;
  const short* Ab = (const short*)Av;
  const int tid = threadIdx.x;
  const int bm = (j / nbx) * 128, bn = (j % nbx) * 128;
  const int wave = tid >> 6, lane = tid & 63;
  const int wm = (wave >> 1) * 64, wn = (wave & 1) * 64;
  const int s = tid & 7;
  const int row0 = tid >> 3;
  f32x4 acc[4][4] = {};
  const int lrow = lane & 15, lk = lane >> 4;

  for (int k0 = 0; k0 < K; k0 += 64){
#pragma unroll
    for (int i = 0; i < 4; i++){
      int row = row0 + i * 32;
      int gr = bm + row;
      int sw = ((s ^ (row & 7)) << 3) + row * 64;
      short8v va = {};
      if (gr < M){
        if (INB){
          va = *(const short8v*)(Ab + (size_t)gr * K + k0 + s * 8);
        } else {
          const float* p = A + (size_t)gr * K + k0 + s * 8;
          float4 x0 = ((const float4*)p)[0], x1 = ((const float4*)p)[1];
          if (ADDA){
            const float* q2 = A2 + (size_t)gr * K + k0 + s * 8;
            float4 y0 = ((const float4*)q2)[0], y1 = ((const float4*)q2)[1];
            x0.x+=y0.x; x0.y+=y0.y; x0.z+=y0.z; x0.w+=y0.w;
            x1.x+=y1.x; x1.y+=y1.y; x1.z+=y1.z; x1.w+=y1.w;
          }
          va = cvt8(x0, x1);
        }
      }
      *(short8v*)&As[sw] = va;
      const float* q = W + (size_t)(bn + row) * K + k0 + s * 8;
      *(short8v*)&Ws[sw] = cvt8(((const float4*)q)[0], ((const float4*)q)[1]);
    }
    __syncthreads();
#pragma unroll
    for (int ks = 0; ks < 2; ks++){
      short8v af[4], bw[4];
      int slot = ks * 4 + lk;
#pragma unroll
      for (int m = 0; m < 4; m++){
        int r = wm + m * 16 + lrow;
        af[m] = *(const short8v*)&As[r * 64 + ((slot ^ (r & 7)) << 3)];
      }
#pragma unroll
      for (int n = 0; n < 4; n++){
        int r = wn + n * 16 + lrow;
        bw[n] = *(const short8v*)&Ws[r * 64 + ((slot ^ (r & 7)) << 3)];
      }
#pragma unroll
      for (int m = 0; m < 4; m++)
#pragma unroll
        for (int n = 0; n < 4; n++)
          acc[m][n] = __builtin_amdgcn_mfma_f32_16x16x32_bf16(
              __builtin_bit_cast(bf16x8, af[m]),
              __builtin_bit_cast(bf16x8, bw[n]), acc[m][n], 0, 0, 0);
    }
    __syncthreads();
  }
  const int STR = 136;
#pragma unroll
  for (int n = 0; n < 4; n++){
    int col = wn + n * 16 + lrow;
    float bsv = bias[bn + col];
#pragma unroll
    for (int m = 0; m < 4; m++){
#pragma unroll
      for (int i = 0; i < 4; i++){
        int row = wm + m * 16 + lk * 4 + i;
        float c = acc[m][n][i] + bsv;
        if (EPI == 1) c = fmaxf(c, 0.f);
        sh[row * STR + col] = f2bf(c);
      }
    }
  }
  __syncthreads();
#pragma unroll
  for (int it = 0; it < 8; it++){
    int r = it * 16 + (tid >> 4);
    int chunk = tid & 15;
    if (bm + r < M){
      uint4 v = *(const uint4*)((const char*)sh + r * 272 + chunk * 16);
      *(uint4*)((char*)Cb + ((size_t)(bm + r) * N + bn) * 2 + chunk * 16) = v;
    }
  }
}

// ---------------- 64x64 MFMA GEMM ----------------
template<int EPI, int OUTB, int INB, int DUALA>
__global__ __launch_bounds__(256) void g64_k(const void* __restrict__ Av,
                                             const void* __restrict__ A1v,
                                             const float* __restrict__ W0,
                                             const float* __restrict__ W1,
                                             int NSPLIT,
                                             const float* __restrict__ bias0,
                                             const float* __restrict__ bias1,
                                             const float* __restrict__ RES,
                                             float* __restrict__ Cf,
                                             __hip_bfloat16* __restrict__ Cb,
                                             int M, int N, int K, int sA){
  __shared__ short sh64[2 * 64 * 64];
  short* As = sh64;
  short* Ws = sh64 + 64 * 64;
  const int tid = threadIdx.x;
  const int bn = blockIdx.x * 64, bm = blockIdx.y * 64;
  const int wave = tid >> 6, lane = tid & 63;
  const int wm = (wave >> 1) * 32, wn = (wave & 1) * 32;
  const int s = tid & 7, row0 = tid >> 3;
  const int lrow = lane & 15, lk = lane >> 4;
  f32x4 acc[2][2] = {};

  for (int k0 = 0; k0 < K; k0 += 64){
#pragma unroll
    for (int i = 0; i < 2; i++){
      int row = row0 + i * 32;
      int sw = ((s ^ (row & 7)) << 3) + row * 64;
      short8v v = {};
      int gr = bm + row;
      if (gr < M){
        if (INB){
          v = *(const short8v*)((const short*)Av + (size_t)gr * sA + k0 + s * 8);
        } else {
          const float* Ap;
          if (DUALA) Ap = (k0 < 256) ? (const float*)Av + (size_t)gr * 256 + k0
                                     : (const float*)A1v + (size_t)gr * 256 + (k0 - 256);
          else Ap = (const float*)Av + (size_t)gr * sA + k0;
          v = cvt8(((const float4*)(Ap + s * 8))[0], ((const float4*)(Ap + s * 8))[1]);
        }
      }
      *(short8v*)&As[sw] = v;
      int wr = bn + row;
      const float* Wp = (wr < NSPLIT) ? W0 + (size_t)wr * K + k0
                                      : W1 + (size_t)(wr - NSPLIT) * K + k0;
      *(short8v*)&Ws[sw] = cvt8(((const float4*)(Wp + s * 8))[0], ((const float4*)(Wp + s * 8))[1]);
    }
    __syncthreads();
#pragma unroll
    for (int ks = 0; ks < 2; ks++){
      int slot = ks * 4 + lk;
      short8v af[2], bw[2];
#pragma unroll
      for (int m = 0; m < 2; m++){
        int r = wm + m * 16 + lrow;
        af[m] = *(const short8v*)&As[r * 64 + ((slot ^ (r & 7)) << 3)];
      }
#pragma unroll
      for (int n = 0; n < 2; n++){
        int r = wn + n * 16 + lrow;
        bw[n] = *(const short8v*)&Ws[r * 64 + ((slot ^ (r & 7)) << 3)];
      }
#pragma unroll
      for (int m = 0; m < 2; m++)
#pragma unroll
        for (int n = 0; n < 2; n++)
          acc[m][n] = __builtin_amdgcn_mfma_f32_16x16x32_bf16(
              __builtin_bit_cast(bf16x8, af[m]),
              __builtin_bit_cast(bf16x8, bw[n]), acc[m][n], 0, 0, 0);
    }
    __syncthreads();
  }
  if (OUTB){
    const int STR = 72;
#pragma unroll
    for (int n = 0; n < 2; n++){
      int col = wn + n * 16 + lrow;
      int gc = bn + col;
      float bsv = (gc < NSPLIT) ? bias0[gc] : bias1[gc - NSPLIT];
#pragma unroll
      for (int m = 0; m < 2; m++){
#pragma unroll
        for (int i = 0; i < 4; i++){
          int row = wm + m * 16 + lk * 4 + i;
          float c = acc[m][n][i] + bsv;
          if (EPI == 1) c = fmaxf(c, 0.f);
          if (EPI == 2) c = 1.f / (1.f + expf(-c));
          sh64[row * STR + col] = f2bf(c);
        }
      }
    }
    __syncthreads();
#pragma unroll
    for (int it = 0; it < 2; it++){
      int r = it * 32 + (tid >> 3);
      int chunk = tid & 7;
      if (bm + r < M){
        uint4 v = *(const uint4*)((const char*)sh64 + r * 144 + chunk * 16);
        *(uint4*)((char*)Cb + ((size_t)(bm + r) * N + bn) * 2 + chunk * 16) = v;
      }
    }
  } else {
#pragma unroll
    for (int n = 0; n < 2; n++){
      int gc = bn + wn + n * 16 + lrow;
      float bsv = (gc < NSPLIT) ? bias0[gc] : bias1[gc - NSPLIT];
#pragma unroll
      for (int m = 0; m < 2; m++){
#pragma unroll
        for (int i = 0; i < 4; i++){
          int row = bm + wm + m * 16 + lk * 4 + i;
          if (row >= M) continue;
          float c = acc[m][n][i] + bsv;
          if (EPI == 1) c = fmaxf(c, 0.f);
          if (EPI == 2) c = 1.f / (1.f + expf(-c));
          if (EPI == 3) c += RES[(size_t)row * N + gc];
          Cf[(size_t)row * N + gc] = c;
        }
      }
    }
  }
}

// -------- fused GEMM (N=256) + residual + LN + permuted write; 32-row tile, 4 waves ----
template<int SITE, int OUTB>
__global__ __launch_bounds__(256) void gln_k(const short* __restrict__ Abf,
                                             const float* __restrict__ W,
                                             const float* __restrict__ bias,
                                             const float* __restrict__ r0,
                                             const float* __restrict__ r1,
                                             const float* __restrict__ g,
                                             const float* __restrict__ be,
                                             void* __restrict__ outv,
                                             int M, int K){
  __shared__ short As[32 * 64];
  __shared__ short Ws[256 * 64];
  __shared__ float part[32][4][2];
  __shared__ float stats[32][2];
  const int tid = threadIdx.x;
  const int bm = blockIdx.x * 32;
  const int wave = tid >> 6, lane = tid & 63;
  const int wn = wave * 64;
  const int s = tid & 7, row0 = tid >> 3;
  const int lrow = lane & 15, lk = lane >> 4;
  f32x4 acc[2][4] = {};

  short8v pa = {};
  { int gr = bm + row0; if (gr < M) pa = *(const short8v*)(Abf + (size_t)gr * K + s * 8); }
  short8v pwb[8];
#pragma unroll
  for (int i = 0; i < 8; i++){
    const float* wp = W + (size_t)(row0 + i * 32) * K + s * 8;
    pwb[i] = cvt8(((const float4*)wp)[0], ((const float4*)wp)[1]);
  }

  for (int k0 = 0; k0 < K; k0 += 64){
    *(short8v*)&As[row0 * 64 + ((s ^ (row0 & 7)) << 3)] = pa;
#pragma unroll
    for (int i = 0; i < 8; i++){
      int row = row0 + i * 32;
      *(short8v*)&Ws[row * 64 + ((s ^ (row & 7)) << 3)] = pwb[i];
    }
    __syncthreads();
    if (k0 + 64 < K){
      int gr = bm + row0;
      pa = (short8v){};
      if (gr < M) pa = *(const short8v*)(Abf + (size_t)gr * K + k0 + 64 + s * 8);
#pragma unroll
      for (int i = 0; i < 8; i++){
        const float* wp = W + (size_t)(row0 + i * 32) * K + k0 + 64 + s * 8;
        pwb[i] = cvt8(((const float4*)wp)[0], ((const float4*)wp)[1]);
      }
    }
#pragma unroll
    for (int ks = 0; ks < 2; ks++){
      int slot = ks * 4 + lk;
      short8v af[2], bw[4];
#pragma unroll
      for (int m = 0; m < 2; m++){
        int r = m * 16 + lrow;
        af[m] = *(const short8v*)&As[r * 64 + ((slot ^ (r & 7)) << 3)];
      }
#pragma unroll
      for (int n = 0; n < 4; n++){
        int r = wn + n * 16 + lrow;
        bw[n] = *(const short8v*)&Ws[r * 64 + ((slot ^ (r & 7)) << 3)];
      }
#pragma unroll
      for (int m = 0; m < 2; m++)
#pragma unroll
        for (int n = 0; n < 4; n++)
          acc[m][n] = __builtin_amdgcn_mfma_f32_16x16x32_bf16(
              __builtin_bit_cast(bf16x8, af[m]),
              __builtin_bit_cast(bf16x8, bw[n]), acc[m][n], 0, 0, 0);
    }
    __syncthreads();
  }

#pragma unroll
  for (int m = 0; m < 2; m++){
#pragma unroll
    for (int i = 0; i < 4; i++){
      int row = m * 16 + lk * 4 + i;
      int grow = bm + row;
      float s1 = 0.f, s2 = 0.f;
      if (grow < M){
#pragma unroll
        for (int n = 0; n < 4; n++){
          int col = wn + n * 16 + lrow;
          float x = acc[m][n][i] + bias[col] + r0[(size_t)grow * 256 + col];
          if (SITE == 0) x += r1[(size_t)grow * 256 + col];
          if (SITE == 2) x = fminf(fmaxf(x, -65504.f), 65504.f);
          acc[m][n][i] = x;
          s1 += x; s2 += x * x;
        }
      }
#pragma unroll
      for (int msk = 1; msk <= 8; msk <<= 1){
        s1 += __shfl_xor(s1, msk, 64);
        s2 += __shfl_xor(s2, msk, 64);
      }
      if (lrow == 0){ part[row][wave][0] = s1; part[row][wave][1] = s2; }
    }
  }
  __syncthreads();
  if (tid < 32){
    float s1 = part[tid][0][0] + part[tid][1][0] + part[tid][2][0] + part[tid][3][0];
    float s2 = part[tid][0][1] + part[tid][1][1] + part[tid][2][1] + part[tid][3][1];
    float mean = s1 * (1.f / 256.f);
    float var = s2 * (1.f / 256.f) - mean * mean;
    stats[tid][0] = mean;
    stats[tid][1] = rsqrtf(fmaxf(var, 0.f) + 1e-5f);
  }
  __syncthreads();
#pragma unroll
  for (int m = 0; m < 2; m++){
#pragma unroll
    for (int i = 0; i < 4; i++){
      int row = m * 16 + lk * 4 + i;
      int grow = bm + row;
      if (grow >= M) continue;
      float mean = stats[row][0], rstd = stats[row][1];
      size_t orow = grow;
      if (SITE == 0){
        int bi = grow / LQ; int rem = grow % LQ; int q = rem / NK_; int kk = rem % NK_;
        orow = (size_t)bi * LQ + kk * NQ_ + q;
      }
#pragma unroll
      for (int n = 0; n < 4; n++){
        int col = wn + n * 16 + lrow;
        float o = (acc[m][n][i] - mean) * rstd * g[col] + be[col];
        if (OUTB) ((short*)outv)[orow * 256 + col] = f2bf(o);
        else      ((float*)outv)[orow * 256 + col] = o;
      }
    }
  }
}

// ---- fused acr out-proj + LN + qpos add + OFFAW GEMM; 32-row tile, 4 waves ----
__global__ __launch_bounds__(256) void glnoa_k(const short* __restrict__ Abf,
                                               const float* __restrict__ W,
                                               const float* __restrict__ bias,
                                               const short* __restrict__ r0b,
                                               const float* __restrict__ qpos,
                                               const float* __restrict__ g,
                                               const float* __restrict__ be,
                                               short* __restrict__ TQout,
                                               float* __restrict__ OFFAW,
                                               const float* __restrict__ off_W,
                                               const float* __restrict__ aw_W,
                                               const float* __restrict__ off_b,
                                               const float* __restrict__ aw_b,
                                               int M){
  __shared__ short smem[32 * 256 + 384 * 64];
  __shared__ float part[32][4][2];
  __shared__ float stats[32][2];
  short* As1 = smem;
  short* Ws1 = smem + 32 * 64;
  short* As2 = smem;
  short* Ws2 = smem + 32 * 256;
  const int K = 256;
  const int tid = threadIdx.x;
  const int bm = blockIdx.x * 32;
  const int wave = tid >> 6, lane = tid & 63;
  const int wn = wave * 64;
  const int s = tid & 7, row0 = tid >> 3;
  const int lrow = lane & 15, lk = lane >> 4;
  f32x4 acc[2][4] = {};

  short8v pa = {};
  { int gr = bm + row0; if (gr < M) pa = *(const short8v*)(Abf + (size_t)gr * K + s * 8); }
  short8v pwb[8];
#pragma unroll
  for (int i = 0; i < 8; i++){
    const float* wp = W + (size_t)(row0 + i * 32) * K + s * 8;
    pwb[i] = cvt8(((const float4*)wp)[0], ((const float4*)wp)[1]);
  }
  for (int k0 = 0; k0 < K; k0 += 64){
    *(short8v*)&As1[row0 * 64 + ((s ^ (row0 & 7)) << 3)] = pa;
#pragma unroll
    for (int i = 0; i < 8; i++){
      int row = row0 + i * 32;
      *(short8v*)&Ws1[row * 64 + ((s ^ (row & 7)) << 3)] = pwb[i];
    }
    __syncthreads();
    if (k0 + 64 < K){
      int gr = bm + row0;
      pa = (short8v){};
      if (gr < M) pa = *(const short8v*)(Abf + (size_t)gr * K + k0 + 64 + s * 8);
#pragma unroll
      for (int i = 0; i < 8; i++){
        const float* wp = W + (size_t)(row0 + i * 32) * K + k0 + 64 + s * 8;
        pwb[i] = cvt8(((const float4*)wp)[0], ((const float4*)wp)[1]);
      }
    }
#pragma unroll
    for (int ks = 0; ks < 2; ks++){
      int slot = ks * 4 + lk;
      short8v af[2], bw[4];
#pragma unroll
      for (int m = 0; m < 2; m++){
        int r = m * 16 + lrow;
        af[m] = *(const short8v*)&As1[r * 64 + ((slot ^ (r & 7)) << 3)];
      }
#pragma unroll
      for (int n = 0; n < 4; n++){
        int r = wn + n * 16 + lrow;
        bw[n] = *(const short8v*)&Ws1[r * 64 + ((slot ^ (r & 7)) << 3)];
      }
#pragma unroll
      for (int m = 0; m < 2; m++)
#pragma unroll
        for (int n = 0; n < 4; n++)
          acc[m][n] = __builtin_amdgcn_mfma_f32_16x16x32_bf16(
              __builtin_bit_cast(bf16x8, af[m]),
              __builtin_bit_cast(bf16x8, bw[n]), acc[m][n], 0, 0, 0);
    }
    __syncthreads();
  }
#pragma unroll
  for (int m = 0; m < 2; m++){
#pragma unroll
    for (int i = 0; i < 4; i++){
      int row = m * 16 + lk * 4 + i;
      int grow = bm + row;
      float s1 = 0.f, s2 = 0.f;
      if (grow < M){
#pragma unroll
        for (int n = 0; n < 4; n++){
          int col = wn + n * 16 + lrow;
          float x = acc[m][n][i] + bias[col] + bf2f(r0b[(size_t)grow * 256 + col]);
          acc[m][n][i] = x;
          s1 += x; s2 += x * x;
        }
      }
#pragma unroll
      for (int msk = 1; msk <= 8; msk <<= 1){
        s1 += __shfl_xor(s1, msk, 64);
        s2 += __shfl_xor(s2, msk, 64);
      }
      if (lrow == 0){ part[row][wave][0] = s1; part[row][wave][1] = s2; }
    }
  }
  __syncthreads();
  if (tid < 32){
    float s1 = part[tid][0][0] + part[tid][1][0] + part[tid][2][0] + part[tid][3][0];
    float s2 = part[tid][0][1] + part[tid][1][1] + part[tid][2][1] + part[tid][3][1];
    float mean = s1 * (1.f / 256.f);
    float var = s2 * (1.f / 256.f) - mean * mean;
    stats[tid][0] = mean;
    stats[tid][1] = rsqrtf(fmaxf(var, 0.f) + 1e-5f);
  }
  __syncthreads();
#pragma unroll
  for (int m = 0; m < 2; m++){
#pragma unroll
    for (int i = 0; i < 4; i++){
      int row = m * 16 + lk * 4 + i;
      int grow = bm + row;
      float mean = stats[row][0], rstd = stats[row][1];
      size_t orow = 0;
      if (grow < M){
        int bi = grow / LQ; int rem = grow % LQ; int kk = rem / NQ_; int q = rem % NQ_;
        orow = (size_t)bi * LQ + q * NK_ + kk;
      }
#pragma unroll
      for (int n = 0; n < 4; n++){
        int col = wn + n * 16 + lrow;
        float tq = 0.f;
        if (grow < M){
          float o = (acc[m][n][i] - mean) * rstd * g[col] + be[col];
          tq = o + qpos[orow * 256 + col];
          TQout[orow * 256 + col] = f2bf(tq);
        }
        As2[row * 256 + ((((col >> 3) ^ (row & 7)) << 3) + (col & 7))] = f2bf(tq);
      }
    }
  }
  __syncthreads();
  const int wn2 = wave * 96;
  f32x4 acc2[2][6] = {};
  for (int k0 = 0; k0 < 256; k0 += 64){
#pragma unroll
    for (int it = 0; it < 12; it++){
      int wr = row0 + it * 32;
      const float* Wp = (wr < 256) ? off_W + (size_t)wr * 256 + k0
                                   : aw_W + (size_t)(wr - 256) * 256 + k0;
      *(short8v*)&Ws2[wr * 64 + ((s ^ (wr & 7)) << 3)] =
          cvt8(((const float4*)(Wp + s * 8))[0], ((const float4*)(Wp + s * 8))[1]);
    }
    __syncthreads();
#pragma unroll
    for (int ks = 0; ks < 2; ks++){
      int slotl = ks * 4 + lk;
      int slotg = (k0 >> 3) + slotl;
      short8v af[2], bw[6];
#pragma unroll
      for (int m = 0; m < 2; m++){
        int r = m * 16 + lrow;
        af[m] = *(const short8v*)&As2[r * 256 + ((slotg ^ (r & 7)) << 3)];
      }
#pragma unroll
      for (int n = 0; n < 6; n++){
        int r = wn2 + n * 16 + lrow;
        bw[n] = *(const short8v*)&Ws2[r * 64 + ((slotl ^ (r & 7)) << 3)];
      }
#pragma unroll
      for (int m = 0; m < 2; m++)
#pragma unroll
        for (int n = 0; n < 6; n++)
          acc2[m][n] = __builtin_amdgcn_mfma_f32_16x16x32_bf16(
              __builtin_bit_cast(bf16x8, af[m]),
              __builtin_bit_cast(bf16x8, bw[n]), acc2[m][n], 0, 0, 0);
    }
    __syncthreads();
  }
#pragma unroll
  for (int m = 0; m < 2; m++){
#pragma unroll
    for (int i = 0; i < 4; i++){
      int row = m * 16 + lk * 4 + i;
      int grow = bm + row;
      if (grow >= M) continue;
      int bi = grow / LQ; int rem = grow % LQ; int kk = rem / NQ_; int q = rem % NQ_;
      size_t orow = (size_t)bi * LQ + q * NK_ + kk;
#pragma unroll
      for (int n = 0; n < 6; n++){
        int col = wn2 + n * 16 + lrow;
        float c = acc2[m][n][i] + ((col < 256) ? off_b[col] : aw_b[col - 256]);
        OFFAW[orow * 384 + col] = c;
      }
    }
  }
}

// ---- fused gate GEMM (K=512) + sigmoid + combine + LN; 32-row tile, 4 waves ----
__global__ __launch_bounds__(256) void gateln_k(const short* __restrict__ TQ,
                                                const short* __restrict__ T2,
                                                const float* __restrict__ W,
                                                const float* __restrict__ bias,
                                                const float* __restrict__ g,
                                                const float* __restrict__ be,
                                                float* __restrict__ out, int M){
  __shared__ short sh[32 * 64 + 512 * 64];
  short* As = sh;
  short* Ws = sh + 32 * 64;
  const int tid = threadIdx.x;
  const int bm = blockIdx.x * 32;
  const int wave = tid >> 6, lane = tid & 63;
  const int wn = wave * 128;
  const int s = tid & 7, row0 = tid >> 3;
  const int lrow = lane & 15, lk = lane >> 4;
  f32x4 acc[2][8] = {};

  for (int k0 = 0; k0 < 512; k0 += 64){
    {
      short8v v = {};
      int gr = bm + row0;
      if (gr < M){
        v = (k0 < 256) ? *(const short8v*)(TQ + (size_t)gr * 256 + k0 + s * 8)
                       : *(const short8v*)(T2 + (size_t)gr * 256 + (k0 - 256) + s * 8);
      }
      *(short8v*)&As[row0 * 64 + ((s ^ (row0 & 7)) << 3)] = v;
    }
#pragma unroll
    for (int i = 0; i < 16; i++){
      int row = row0 + i * 32;
      const float* wp = W + (size_t)row * 512 + k0 + s * 8;
      *(short8v*)&Ws[row * 64 + ((s ^ (row & 7)) << 3)] =
          cvt8(((const float4*)wp)[0], ((const float4*)wp)[1]);
    }
    __syncthreads();
#pragma unroll
    for (int ks = 0; ks < 2; ks++){
      int slot = ks * 4 + lk;
      short8v af[2], bw[8];
#pragma unroll
      for (int m = 0; m < 2; m++){
        int r = m * 16 + lrow;
        af[m] = *(const short8v*)&As[r * 64 + ((slot ^ (r & 7)) << 3)];
      }
#pragma unroll
      for (int n = 0; n < 8; n++){
        int r = wn + n * 16 + lrow;
        bw[n] = *(const short8v*)&Ws[r * 64 + ((slot ^ (r & 7)) << 3)];
      }
#pragma unroll
      for (int m = 0; m < 2; m++)
#pragma unroll
        for (int n = 0; n < 8; n++)
          acc[m][n] = __builtin_amdgcn_mfma_f32_16x16x32_bf16(
              __builtin_bit_cast(bf16x8, af[m]),
              __builtin_bit_cast(bf16x8, bw[n]), acc[m][n], 0, 0, 0);
    }
    __syncthreads();
  }
  short* gb = sh;
  const int GSTR = 520;
#pragma unroll
  for (int n = 0; n < 8; n++){
    int col = wn + n * 16 + lrow;
    float bsv = bias[col];
#pragma unroll
    for (int m = 0; m < 2; m++){
#pragma unroll
      for (int i = 0; i < 4; i++){
        int row = m * 16 + lk * 4 + i;
        float c = acc[m][n][i] + bsv;
        gb[row * GSTR + col] = f2bf(1.f / (1.f + __expf(-c)));
      }
    }
  }
  __syncthreads();
  {
    int row = tid >> 3, cg = tid & 7;
    int grow = bm + row;
    float x[32];
    float s1 = 0.f, s2 = 0.f;
    if (grow < M){
#pragma unroll
      for (int jv = 0; jv < 4; jv++){
        int c0 = cg * 32 + jv * 8;
        short8v aqv = *(const short8v*)(TQ + (size_t)grow * 256 + c0);
        short8v t2v = *(const short8v*)(T2 + (size_t)grow * 256 + c0);
#pragma unroll
        for (int jj = 0; jj < 8; jj++){
          float g1 = bf2f(gb[row * GSTR + c0 + jj]);
          float g2 = bf2f(gb[row * GSTR + 256 + c0 + jj]);
          float xv = g1 * bf2f(aqv[jj]) + g2 * bf2f(t2v[jj]);
          x[jv * 8 + jj] = xv; s1 += xv; s2 += xv * xv;
        }
      }
    }
    s1 += __shfl_xor(s1, 1, 64); s2 += __shfl_xor(s2, 1, 64);
    s1 += __shfl_xor(s1, 2, 64); s2 += __shfl_xor(s2, 2, 64);
    s1 += __shfl_xor(s1, 4, 64); s2 += __shfl_xor(s2, 4, 64);
    float mean = s1 * (1.f / 256.f);
    float var = s2 * (1.f / 256.f) - mean * mean;
    float rstd = rsqrtf(fmaxf(var, 0.f) + 1e-5f);
    if (grow < M){
#pragma unroll
      for (int jv = 0; jv < 4; jv++){
        int c0 = cg * 32 + jv * 8;
        float4 o0, o1;
#pragma unroll
        for (int jj = 0; jj < 8; jj++){
          int c = c0 + jj;
          float o = (x[jv * 8 + jj] - mean) * rstd * g[c] + be[c];
          if (jj < 4) ((float*)&o0)[jj] = o; else ((float*)&o1)[jj - 4] = o;
        }
        *(float4*)(out + (size_t)grow * 256 + c0) = o0;
        *(float4*)(out + (size_t)grow * 256 + c0 + 4) = o1;
      }
    }
  }
}

// ---------------- MFMA MHA ----------------
template<int TP, int NSPL>
__global__ __launch_bounds__(256) void mha_mfma_k(const short* __restrict__ qkv,
                                                  __hip_bfloat16* __restrict__ out, int S){
  constexpr int MT = TP / 16;
  constexpr int KSTEPS = (TP + 31) / 32;
  constexpr int KS32 = KSTEPS * 32;
  constexpr int VSTRB = (KS32 == 128) ? 256 : 128;
  constexpr int CH = (MT + NSPL - 1) / NSPL;
  __shared__ short QK[2][TP][64];
  __shared__ short Vt[2][32][VSTRB / 2];
  __shared__ float Sc[2][16][128];
  __shared__ float rinv[2][16];

  const int tid = threadIdx.x;
  const int bid = blockIdx.x;
  const int batch = bid / (4 * NSPL);
  const int rem = bid % (4 * NSPL);
  const int hp = rem / NSPL;
  const int half = rem % NSPL;
  const int mtlo = half * CH;
  const int mthi = (mtlo + CH < MT) ? (mtlo + CH) : MT;
  const int wave = tid >> 6, lane = tid & 63;
  const int hh = wave >> 1, wsub = wave & 1;
  const int lrow = lane & 15, lk = lane >> 4;
  const float scale = 0.17677669529663687f;
  const size_t qbase = (size_t)batch * S * 768;

  for (int idx = tid; idx < 2 * TP * 4; idx += 256){
    int h2 = idx >= TP * 4;
    int rm = idx - h2 * TP * 4;
    int j = rm >> 2, s = rm & 3;
    int h = hp * 2 + h2;
    short8v qv = {}, kv = {};
    if (j < S){
      const short* p = qkv + qbase + (size_t)j * 768 + h * 32 + s * 8;
      qv = *(const short8v*)p;
      kv = *(const short8v*)(p + 256);
    }
    *(short8v*)&QK[h2][j][(s ^ (j & 7)) << 3] = qv;
    *(short8v*)&QK[h2][j][((s + 4) ^ (j & 7)) << 3] = kv;
  }
  for (int idx = tid; idx < 2 * KS32 * 4; idx += 256){
    int h2 = idx >= KS32 * 4;
    int rm = idx - h2 * KS32 * 4;
    int j = rm >> 2, e8 = rm & 3;
    int h = hp * 2 + h2;
    short8v v = {};
    if (j < S) v = *(const short8v*)(qkv + qbase + (size_t)j * 768 + h * 32 + 512 + e8 * 8);
#pragma unroll
    for (int c = 0; c < 8; c++){
      int e = e8 * 8 + c;
      char* pb = (char*)&Vt[h2][0][0] + e * VSTRB + (((j >> 3) ^ (e & 7)) << 4) + ((j & 7) << 1);
      *(short*)pb = v[c];
    }
  }
  __syncthreads();

  for (int mt = mtlo; mt < mthi; mt++){
    for (int nt = wsub; nt < MT; nt += 2){
      int ar = mt * 16 + lrow;
      short8v aq = *(const short8v*)&QK[hh][ar][(lk ^ (ar & 7)) << 3];
      int br = nt * 16 + lrow;
      short8v bk = *(const short8v*)&QK[hh][br][((lk + 4) ^ (br & 7)) << 3];
      f32x4 z = {};
      f32x4 d = __builtin_amdgcn_mfma_f32_16x16x32_bf16(
          __builtin_bit_cast(bf16x8, aq), __builtin_bit_cast(bf16x8, bk), z, 0, 0, 0);
#pragma unroll
      for (int i = 0; i < 4; i++){
        int rr = lk * 4 + i;
        int c = nt * 16 + lrow;
        Sc[hh][rr][(((c >> 2) ^ (rr & 7)) << 2) + (c & 3)] = d[i] * scale;
      }
    }
    __syncthreads();
    if (wsub == 0){
      int rr = lane >> 2, p = lane & 3;
      int grow = mt * 16 + rr;
      int Seff = (grow < S) ? S : 0;
      float mx = -1e30f;
#pragma unroll
      for (int m = 0; m < KSTEPS; m++){
        int j = p + 4 * m;
#pragma unroll
        for (int hf = 0; hf < 2; hf++){
          int ls = 2 * j + hf;
          float4 v = *(const float4*)&Sc[hh][rr][(ls ^ (rr & 7)) << 2];
          int c0 = ls * 4;
          mx = fmaxf(mx, (c0 + 0 < Seff) ? v.x : -1e30f);
          mx = fmaxf(mx, (c0 + 1 < Seff) ? v.y : -1e30f);
          mx = fmaxf(mx, (c0 + 2 < Seff) ? v.z : -1e30f);
          mx = fmaxf(mx, (c0 + 3 < Seff) ? v.w : -1e30f);
        }
      }
      mx = fmaxf(mx, __shfl_xor(mx, 1, 64));
      mx = fmaxf(mx, __shfl_xor(mx, 2, 64));
      float sum = 0.f;
#pragma unroll
      for (int m = 0; m < KSTEPS; m++){
        int j = p + 4 * m;
        float ev[8];
#pragma unroll
        for (int hf = 0; hf < 2; hf++){
          int ls = 2 * j + hf;
          float4 v = *(const float4*)&Sc[hh][rr][(ls ^ (rr & 7)) << 2];
          int c0 = ls * 4;
          ev[hf * 4 + 0] = (c0 + 0 < Seff) ? __expf(v.x - mx) : 0.f;
          ev[hf * 4 + 1] = (c0 + 1 < Seff) ? __expf(v.y - mx) : 0.f;
          ev[hf * 4 + 2] = (c0 + 2 < Seff) ? __expf(v.z - mx) : 0.f;
          ev[hf * 4 + 3] = (c0 + 3 < Seff) ? __expf(v.w - mx) : 0.f;
        }
        short8v pb;
#pragma unroll
        for (int q2 = 0; q2 < 8; q2++){ pb[q2] = f2bf(ev[q2]); sum += ev[q2]; }
        *(short8v*)((char*)&Sc[hh][rr][0] + ((j ^ (rr & 7)) << 4)) = pb;
      }
      sum += __shfl_xor(sum, 1, 64);
      sum += __shfl_xor(sum, 2, 64);
      if (p == 0) rinv[hh][rr] = (sum > 0.f) ? 1.f / sum : 0.f;
    }
    __syncthreads();
    {
      int nt2 = wsub;
      f32x4 acc = {};
#pragma unroll
      for (int ks = 0; ks < KSTEPS; ks++){
        int slot = ks * 4 + lk;
        short8v ap = *(const short8v*)((const char*)&Sc[hh][lrow][0] + ((slot ^ (lrow & 7)) << 4));
        int e = nt2 * 16 + lrow;
        short8v bv = *(const short8v*)((const char*)&Vt[hh][0][0] + e * VSTRB + ((slot ^ (e & 7)) << 4));
        acc = __builtin_amdgcn_mfma_f32_16x16x32_bf16(
            __builtin_bit_cast(bf16x8, ap), __builtin_bit_cast(bf16x8, bv), acc, 0, 0, 0);
      }
      int h = hp * 2 + hh;
#pragma unroll
      for (int i = 0; i < 4; i++){
        int row = mt * 16 + lk * 4 + i;
        if (row < S){
          float rv = rinv[hh][lk * 4 + i];
          out[((size_t)batch * S + row) * 256 + h * 32 + nt2 * 16 + lrow] =
              __float2bfloat16(acc[i] * rv);
        }
      }
    }
    __syncthreads();
  }
}

// ---------------- deformable sampling, two-phase; bf16 out ----------------
__global__ __launch_bounds__(256) void deform_k(const __hip_bfloat16* __restrict__ val,
                                                const float* __restrict__ offaw,
                                                const float* __restrict__ ref,
                                                unsigned int* __restrict__ outb){
  __shared__ uint2 meta[32][16][4];
  const int tid = threadIdx.x;
  const int t0 = blockIdx.x * 4;
  {
    int g = tid >> 3;
    int pair = tid & 7;
    int lt = g >> 3, h = g & 7;
    int t = t0 + lt;
    int b = t / LQ;
    int p0 = pair * 2;
    int l = p0 >> 2;
    const int starts[4] = {0, 25600, 32000, 33600};
    const int HS[4] = {160, 80, 40, 20};
    int w = HS[l];
    const float* ap = offaw + (size_t)t * 384 + 256 + h * 16;
    float a0 = ap[p0];
    float a1 = ap[p0 + 1];
    float mx = fmaxf(a0, a1);
#pragma unroll
    for (int m = 1; m <= 4; m <<= 1) mx = fmaxf(mx, __shfl_xor(mx, m, 64));
    float e0 = expf(a0 - mx), e1 = expf(a1 - mx);
    float s = e0 + e1;
#pragma unroll
    for (int m = 1; m <= 4; m <<= 1) s += __shfl_xor(s, m, 64);
    float inv = 1.f / s;
    float rx = ref[((size_t)t * 4 + l) * 2 + 0];
    float ry = ref[((size_t)t * 4 + l) * 2 + 1];
    float4 ov = *(const float4*)(offaw + (size_t)t * 384 + h * 32 + l * 8 + p0 * 2);
    int vbase = (b * LEN_VV + starts[l]) * 128 + h * 16;
#pragma unroll
    for (int pp = 0; pp < 2; pp++){
      float wgt = (pp ? e1 : e0) * inv;
      float px = rx * w + (pp ? ov.z : ov.x) - 0.5f;
      float py = ry * w + (pp ? ov.w : ov.y) - 0.5f;
      float x0f = floorf(px), y0f = floorf(py);
      float lx = px - x0f, ly = py - y0f;
      int x0 = (int)x0f, y0 = (int)y0f;
#pragma unroll
      for (int c = 0; c < 4; c++){
        int dx = c & 1, dy = c >> 1;
        int xi = x0 + dx, yi = y0 + dy;
        bool ok = (xi >= 0) & (xi < w) & (yi >= 0) & (yi < w);
        float cw = ok ? wgt * (dx ? lx : 1.f - lx) * (dy ? ly : 1.f - ly) : 0.f;
        uint idx = ok ? (uint)(vbase + (yi * w + xi) * 128) : 0u;
        uint2 m2; m2.x = idx; m2.y = __float_as_uint(cw);
        meta[g][p0 + pp][c] = m2;
      }
    }
  }
  __syncthreads();
  const uint2* V2 = (const uint2*)val;
  int sg = tid >> 3, lane8 = tid & 7;
  int lt = sg >> 3, h = sg & 7;
  int t = t0 + lt;
  float a0 = 0.f, a1 = 0.f, a2 = 0.f, a3 = 0.f;
#pragma unroll 4
  for (int c = 0; c < 64; c++){
    uint2 mw = meta[sg][c >> 2][c & 3];
    float wv = __uint_as_float(mw.y);
    uint2 v = V2[(size_t)(mw.x >> 1) + lane8];
    a0 += wv * __uint_as_float(v.x << 16);
    a1 += wv * __uint_as_float(v.x & 0xffff0000u);
    a2 += wv * __uint_as_float(v.y << 16);
    a3 += wv * __uint_as_float(v.y & 0xffff0000u);
  }
  uint2 u;
  u.x = ((uint)(unsigned short)f2bf(a1) << 16) | (uint)(unsigned short)f2bf(a0);
  u.y = ((uint)(unsigned short)f2bf(a3) << 16) | (uint)(unsigned short)f2bf(a2);
  ((uint2*)outb)[((size_t)t * 256 + h * 32) / 4 + lane8] = u;
}

extern "C" void kernel_launch(void* const* d_in, const int* in_sizes, int n_in,
                              void* d_out, int out_size, void* d_ws, size_t ws_size,
                              hipStream_t stream){
  const float* tgt_pose = (const float*)d_in[0];
  const float* qpos     = (const float*)d_in[1];
  const float* refp     = (const float*)d_in[2];
  const float* memory   = (const float*)d_in[3];
  const float* win_Wqkv = (const float*)d_in[4];
  const float* win_bqkv = (const float*)d_in[5];
  const float* win_Wo   = (const float*)d_in[6];
  const float* win_bo   = (const float*)d_in[7];
  const float* win_ng   = (const float*)d_in[8];
  const float* win_nb   = (const float*)d_in[9];
  const float* acr_Wqkv = (const float*)d_in[10];
  const float* acr_bqkv = (const float*)d_in[11];
  const float* acr_Wo   = (const float*)d_in[12];
  const float* acr_bo   = (const float*)d_in[13];
  const float* acr_ng   = (const float*)d_in[14];
  const float* acr_nb   = (const float*)d_in[15];
  const float* off_W    = (const float*)d_in[16];
  const float* off_b    = (const float*)d_in[17];
  const float* aw_W     = (const float*)d_in[18];
  const float* aw_b     = (const float*)d_in[19];
  const float* val_W    = (const float*)d_in[20];
  const float* val_b    = (const float*)d_in[21];
  const float* outp_W   = (const float*)d_in[22];
  const float* outp_b   = (const float*)d_in[23];
  const float* gate_W   = (const float*)d_in[24];
  const float* gate_b   = (const float*)d_in[25];
  const float* gate_ng  = (const float*)d_in[26];
  const float* gate_nb  = (const float*)d_in[27];
  const float* ffn_W1   = (const float*)d_in[28];
  const float* ffn_b1   = (const float*)d_in[29];
  const float* ffn_W2   = (const float*)d_in[30];
  const float* ffn_b2   = (const float*)d_in[31];
  const float* n2_g     = (const float*)d_in[32];
  const float* n2_b     = (const float*)d_in[33];

  float* out = (float*)d_out;
  char* ws = (char*)d_ws;
  const size_t TB = (size_t)T_TOK * 256 * 4;
  float* B2 = (float*)(ws);                                 // fp32 tgt3
  char* p = ws + TB;
  short* B1b = (short*)p;  p += (size_t)T_TOK * 256 * 2;    // bf16 tgt1 (b,k,q)
  short* Qb  = (short*)p;  p += (size_t)T_TOK * 768 * 2;    // bf16 qkv
  short* ABF = (short*)p;  p += (size_t)T_TOK * 256 * 2;    // bf16 attn/deform out
  short* TQb = (short*)p;  p += (size_t)T_TOK * 256 * 2;    // bf16 tgt_q
  short* T2b = (short*)p;  p += (size_t)T_TOK * 256 * 2;    // bf16 t2
  float* OFFAW = (float*)p; p += (size_t)T_TOK * 384 * 4;   // off|aw logits
  char* Vregion = p;
  __hip_bfloat16* V = (__hip_bfloat16*)Vregion;             // 139 MB
  short* FF = (short*)Vregion;                              // overlay (V dead after deform)

  const int GM128 = (T_TOK + 127) / 128;   // 107
  const int GM64  = (T_TOK + 63) / 64;     // 213
  const int GM32  = (T_TOK + 31) / 32;     // 425
  const int BIG = 1 << 30;

  // 1. value proj (XCD-swizzled, low-VGPR no-prefetch) -> V bf16
  mgemm_k<0,0,1,0><<<2 * 2125, 256, 0, stream>>>(memory, nullptr, val_W, val_b, V, BS_ * LEN_VV, 256, 256, 2);
  // 2. within qkv (A = tgt_pose + qpos fused) -> Qb
  mgemm_k<0,1,0,0><<<6 * GM128, 256, 0, stream>>>(tgt_pose, qpos, win_Wqkv, win_bqkv, (__hip_bfloat16*)Qb, T_TOK, 768, 256, 6);
  // 3. within attention (S=17)
  mha_mfma_k<32,1><<<800 * 4, 256, 0, stream>>>(Qb, (__hip_bfloat16*)ABF, 17);
  // 4. out proj + LN(tgt_pose+qpos+C) + transpose write -> B1b bf16 (b,k,q)
  gln_k<0,1><<<GM32, 256, 0, stream>>>(ABF, win_Wo, win_bo, tgt_pose, qpos, win_ng, win_nb, B1b, T_TOK, 256);
  // 5. across qkv (A = B1b bf16) -> Qb
  mgemm_k<0,0,0,1><<<6 * GM128, 256, 0, stream>>>(B1b, nullptr, acr_Wqkv, acr_bqkv, (__hip_bfloat16*)Qb, T_TOK, 768, 256, 6);
  // 6. across attention (S=100)
  mha_mfma_k<112,2><<<136 * 8, 256, 0, stream>>>(Qb, (__hip_bfloat16*)ABF, 100);
  // 7. out proj + LN + un-transpose + qpos add -> TQb ; + OFFAW GEMM fused
  glnoa_k<<<GM32, 256, 0, stream>>>(ABF, acr_Wo, acr_bo, B1b, qpos, acr_ng, acr_nb,
                                    TQb, OFFAW, off_W, aw_W, off_b, aw_b, T_TOK);
  // 8. deformable sampling -> ABF bf16
  deform_k<<<T_TOK / 4, 256, 0, stream>>>(V, OFFAW, refp, (unsigned int*)ABF);
  // 9. output proj of deformable attn -> T2b bf16
  g64_k<0,1,1,0><<<dim3(4, GM64), 256, 0, stream>>>(ABF, nullptr, outp_W, outp_W, BIG, outp_b, outp_b, nullptr, nullptr, (__hip_bfloat16*)T2b, T_TOK, 256, 256, 256);
  // 10. fused gate GEMM + sigmoid + combine + LN -> B2 fp32
  gateln_k<<<GM32, 256, 0, stream>>>(TQb, T2b, gate_W, gate_b, gate_ng, gate_nb, B2, T_TOK);
  // 11. FFN up (relu, bf16 out) -> FF
  mgemm_k<1,0,0,0><<<8 * GM128, 256, 0, stream>>>(B2, nullptr, ffn_W1, ffn_b1, (__hip_bfloat16*)FF, T_TOK, 1024, 256, 8);
  // 12. FFN down + residual(B2) + clip + final LN -> out
  gln_k<2,0><<<GM32, 256, 0, stream>>>(FF, ffn_W2, ffn_b2, B2, nullptr, n2_g, n2_b, out, T_TOK, 1024);
}